// Round 1
// baseline (24002.994 us; speedup 1.0000x reference)
//
#include <hip/hip_runtime.h>
#include <hip/hip_bf16.h>

#define Bb 8
#define Nn 512
#define Dd 768
#define Hh 12
#define Yy 64
#define Mm 3072
#define BN_TOT (Bb*Nn)   /* 4096 */
#define HY (Hh*Yy)       /* 768 */
#define ALPHA 0.1f
#define BETA 0.125f
#define LN_EPS 1e-5f

#define TILE 64
#define TILE_K 16

// ---------------------------------------------------------------- LayerNorm
__global__ __launch_bounds__(256) void k_ln(const float* __restrict__ x,
                                            const float* __restrict__ gamma,
                                            const float* __restrict__ delta,
                                            float* __restrict__ g) {
  int row = blockIdx.x;                       // 0..4095
  const float* xr = x + (size_t)row * Dd;
  float* gr = g + (size_t)row * Dd;
  int t = threadIdx.x;
  float v0 = xr[t], v1 = xr[t + 256], v2 = xr[t + 512];
  float s = v0 + v1 + v2;
  float ss = v0 * v0 + v1 * v1 + v2 * v2;
#pragma unroll
  for (int o = 32; o; o >>= 1) {
    s += __shfl_xor(s, o);
    ss += __shfl_xor(ss, o);
  }
  __shared__ float red[8];
  int wave = t >> 6;
  if ((t & 63) == 0) { red[wave] = s; red[4 + wave] = ss; }
  __syncthreads();
  float ts = red[0] + red[1] + red[2] + red[3];
  float tss = red[4] + red[5] + red[6] + red[7];
  float mu = ts * (1.0f / Dd);
  float var = tss * (1.0f / Dd) - mu * mu;
  float rstd = rsqrtf(var + LN_EPS);
  gr[t]       = gamma[t]       * (v0 - mu) * rstd + delta[t];
  gr[t + 256] = gamma[t + 256] * (v1 - mu) * rstd + delta[t + 256];
  gr[t + 512] = gamma[t + 512] * (v2 - mu) * rstd + delta[t + 512];
}

// ------------------------------------------------------------ GEMM helpers
// As[k][m] = A[(row0+m)*lda + k0+k]   (contraction over A's FAST axis)
__device__ __forceinline__ void loadA_fastK(float As[TILE_K][TILE + 1],
                                            const float* __restrict__ A, int lda,
                                            int row0, int k0, int tid) {
#pragma unroll
  for (int i = 0; i < 4; ++i) {
    int e = tid + i * 256;
    int m = e >> 4, k = e & 15;
    As[k][m] = A[(size_t)(row0 + m) * lda + k0 + k];
  }
}
// Bs[k][n] = Bm[(k0+k)*ldb + n0+n]    (contraction over B's SLOW axis)
__device__ __forceinline__ void loadB_fastN(float Bs[TILE_K][TILE + 1],
                                            const float* __restrict__ Bm, int ldb,
                                            int k0, int n0, int tid) {
#pragma unroll
  for (int i = 0; i < 4; ++i) {
    int e = tid + i * 256;
    int k = e >> 6, n = e & 63;
    Bs[k][n] = Bm[(size_t)(k0 + k) * ldb + n0 + n];
  }
}

__device__ __forceinline__ void mm16(const float As[TILE_K][TILE + 1],
                                     const float Bs[TILE_K][TILE + 1],
                                     float acc[4][4], int tx, int ty) {
#pragma unroll
  for (int k = 0; k < TILE_K; ++k) {
    float a[4], b[4];
#pragma unroll
    for (int i = 0; i < 4; ++i) a[i] = As[k][ty * 4 + i];
#pragma unroll
    for (int j = 0; j < 4; ++j) b[j] = Bs[k][tx * 4 + j];
#pragma unroll
    for (int i = 0; i < 4; ++i)
#pragma unroll
      for (int j = 0; j < 4; ++j) acc[i][j] += a[i] * b[j];
  }
}

// ---------------------------------------------------- q/k projection (A·Wᵀ)
// q[bn,hy] = sum_d g[bn,d]*Wq[hy,d];  z=0 -> q, z=1 -> k
__global__ __launch_bounds__(256) void k_qkproj(const float* __restrict__ g,
                                                const float* __restrict__ Wq,
                                                const float* __restrict__ Wk,
                                                float* __restrict__ q,
                                                float* __restrict__ k) {
  const float* W = blockIdx.z ? Wk : Wq;
  float* out = blockIdx.z ? k : q;
  __shared__ float As[TILE_K][TILE + 1], Bs[TILE_K][TILE + 1];
  int tid = threadIdx.x, tx = tid & 15, ty = tid >> 4;
  int n0 = blockIdx.x * TILE, row0 = blockIdx.y * TILE;
  float acc[4][4] = {};
  for (int k0 = 0; k0 < Dd; k0 += TILE_K) {
    loadA_fastK(As, g, Dd, row0, k0, tid);
    loadA_fastK(Bs, W, Dd, n0, k0, tid);
    __syncthreads();
    mm16(As, Bs, acc, tx, ty);
    __syncthreads();
  }
#pragma unroll
  for (int i = 0; i < 4; ++i)
#pragma unroll
    for (int j = 0; j < 4; ++j)
      out[(size_t)(row0 + ty * 4 + i) * HY + n0 + tx * 4 + j] = acc[i][j];
}

// -------------------------------------------------------- scores (β·q·kᵀ)
// per batch b: S[h][n][m] = β Σ_y q[n, h*64+y] k[m, h*64+y]
__global__ __launch_bounds__(256) void k_scores(const float* __restrict__ qb,
                                                const float* __restrict__ kb,
                                                float* __restrict__ P) {
  int h = blockIdx.z;
  const float* A = qb + h * Yy;
  const float* Bm = kb + h * Yy;
  float* S = P + (size_t)h * Nn * Nn;
  __shared__ float As[TILE_K][TILE + 1], Bs[TILE_K][TILE + 1];
  int tid = threadIdx.x, tx = tid & 15, ty = tid >> 4;
  int n0 = blockIdx.x * TILE, row0 = blockIdx.y * TILE;
  float acc[4][4] = {};
  for (int k0 = 0; k0 < Yy; k0 += TILE_K) {
    loadA_fastK(As, A, HY, row0, k0, tid);
    loadA_fastK(Bs, Bm, HY, n0, k0, tid);
    __syncthreads();
    mm16(As, Bs, acc, tx, ty);
    __syncthreads();
  }
#pragma unroll
  for (int i = 0; i < 4; ++i)
#pragma unroll
    for (int j = 0; j < 4; ++j)
      S[(size_t)(row0 + ty * 4 + i) * Nn + n0 + tx * 4 + j] = BETA * acc[i][j];
}

// ------------------------------------------------------------- row softmax
__global__ __launch_bounds__(256) void k_softmax(float* __restrict__ P) {
  float* row = P + (size_t)blockIdx.y * Nn * Nn + (size_t)blockIdx.x * Nn;
  int t = threadIdx.x;
  float a = row[t], b = row[t + 256];
  float mx = fmaxf(a, b);
#pragma unroll
  for (int o = 32; o; o >>= 1) mx = fmaxf(mx, __shfl_xor(mx, o));
  __shared__ float rm[4], rs[4];
  int wave = t >> 6;
  if ((t & 63) == 0) rm[wave] = mx;
  __syncthreads();
  mx = fmaxf(fmaxf(rm[0], rm[1]), fmaxf(rm[2], rm[3]));
  float ea = __expf(a - mx), eb = __expf(b - mx);
  float s = ea + eb;
#pragma unroll
  for (int o = 32; o; o >>= 1) s += __shfl_xor(s, o);
  if ((t & 63) == 0) rs[wave] = s;
  __syncthreads();
  float inv = 1.0f / (rs[0] + rs[1] + rs[2] + rs[3]);
  row[t] = ea * inv;
  row[t + 256] = eb * inv;
}

// ------------------------------------------------------------ dq = P·K
// dq[n, h*64+y] = Σ_m P[h][n][m] k[m, h*64+y]
__global__ __launch_bounds__(256) void k_dq(const float* __restrict__ P,
                                            const float* __restrict__ kb,
                                            float* __restrict__ dqb) {
  int h = blockIdx.z;
  const float* A = P + (size_t)h * Nn * Nn;   // [n][m], lda=Nn
  const float* Bm = kb + h * Yy;              // [m][y], ldb=HY
  __shared__ float As[TILE_K][TILE + 1], Bs[TILE_K][TILE + 1];
  int tid = threadIdx.x, tx = tid & 15, ty = tid >> 4;
  int row0 = blockIdx.y * TILE;
  float acc[4][4] = {};
  for (int k0 = 0; k0 < Nn; k0 += TILE_K) {
    loadA_fastK(As, A, Nn, row0, k0, tid);
    loadB_fastN(Bs, Bm, HY, k0, 0, tid);
    __syncthreads();
    mm16(As, Bs, acc, tx, ty);
    __syncthreads();
  }
#pragma unroll
  for (int i = 0; i < 4; ++i)
#pragma unroll
    for (int j = 0; j < 4; ++j)
      dqb[(size_t)(row0 + ty * 4 + i) * HY + h * Yy + tx * 4 + j] = acc[i][j];
}

// ------------------------------------------------------------ dk = Pᵀ·Q
// dk[m, h*64+y] = Σ_n P[h][n][m] q[n, h*64+y]
__global__ __launch_bounds__(256) void k_dk(const float* __restrict__ P,
                                            const float* __restrict__ qb,
                                            float* __restrict__ dkb) {
  int h = blockIdx.z;
  const float* A = P + (size_t)h * Nn * Nn;   // accessed [n][m], contraction over n
  const float* Bm = qb + h * Yy;
  __shared__ float As[TILE_K][TILE + 1], Bs[TILE_K][TILE + 1];
  int tid = threadIdx.x, tx = tid & 15, ty = tid >> 4;
  int row0 = blockIdx.y * TILE;               // m tile
  float acc[4][4] = {};
  for (int k0 = 0; k0 < Nn; k0 += TILE_K) {
    loadB_fastN(As, A, Nn, k0, row0, tid);    // As[k][m] = P[(k0+k)][row0+m]
    loadB_fastN(Bs, Bm, HY, k0, 0, tid);
    __syncthreads();
    mm16(As, Bs, acc, tx, ty);
    __syncthreads();
  }
#pragma unroll
  for (int i = 0; i < 4; ++i)
#pragma unroll
    for (int j = 0; j < 4; ++j)
      dkb[(size_t)(row0 + ty * 4 + i) * HY + h * Yy + tx * 4 + j] = acc[i][j];
}

// ---------------------------------------- x += α(dq·Wq + dk·Wk)  [hy contraction]
__global__ __launch_bounds__(256) void k_upd2(const float* __restrict__ dq,
                                              const float* __restrict__ dk,
                                              const float* __restrict__ Wq,
                                              const float* __restrict__ Wk,
                                              float* __restrict__ x) {
  __shared__ float As[TILE_K][TILE + 1], Bs[TILE_K][TILE + 1];
  int tid = threadIdx.x, tx = tid & 15, ty = tid >> 4;
  int n0 = blockIdx.x * TILE, row0 = blockIdx.y * TILE;
  float acc[4][4] = {};
  for (int k0 = 0; k0 < HY; k0 += TILE_K) {
    loadA_fastK(As, dq, HY, row0, k0, tid);
    loadB_fastN(Bs, Wq, Dd, k0, n0, tid);
    __syncthreads();
    mm16(As, Bs, acc, tx, ty);
    __syncthreads();
    loadA_fastK(As, dk, HY, row0, k0, tid);
    loadB_fastN(Bs, Wk, Dd, k0, n0, tid);
    __syncthreads();
    mm16(As, Bs, acc, tx, ty);
    __syncthreads();
  }
#pragma unroll
  for (int i = 0; i < 4; ++i)
#pragma unroll
    for (int j = 0; j < 4; ++j)
      x[(size_t)(row0 + ty * 4 + i) * Dd + n0 + tx * 4 + j] += ALPHA * acc[i][j];
}

// ----------------------------------------------- hid = relu(g·xiᵀ)
__global__ __launch_bounds__(256) void k_hid(const float* __restrict__ g,
                                             const float* __restrict__ xi,
                                             float* __restrict__ hid) {
  __shared__ float As[TILE_K][TILE + 1], Bs[TILE_K][TILE + 1];
  int tid = threadIdx.x, tx = tid & 15, ty = tid >> 4;
  int n0 = blockIdx.x * TILE, row0 = blockIdx.y * TILE;
  float acc[4][4] = {};
  for (int k0 = 0; k0 < Dd; k0 += TILE_K) {
    loadA_fastK(As, g, Dd, row0, k0, tid);
    loadA_fastK(Bs, xi, Dd, n0, k0, tid);
    __syncthreads();
    mm16(As, Bs, acc, tx, ty);
    __syncthreads();
  }
#pragma unroll
  for (int i = 0; i < 4; ++i)
#pragma unroll
    for (int j = 0; j < 4; ++j)
      hid[(size_t)(row0 + ty * 4 + i) * Mm + n0 + tx * 4 + j] = fmaxf(acc[i][j], 0.0f);
}

// ----------------------------------------------- x += α·hid·xi  [m contraction]
__global__ __launch_bounds__(256) void k_updhid(const float* __restrict__ hid,
                                                const float* __restrict__ xi,
                                                float* __restrict__ x) {
  __shared__ float As[TILE_K][TILE + 1], Bs[TILE_K][TILE + 1];
  int tid = threadIdx.x, tx = tid & 15, ty = tid >> 4;
  int n0 = blockIdx.x * TILE, row0 = blockIdx.y * TILE;
  float acc[4][4] = {};
  for (int k0 = 0; k0 < Mm; k0 += TILE_K) {
    loadA_fastK(As, hid, Mm, row0, k0, tid);
    loadB_fastN(Bs, xi, Dd, k0, n0, tid);
    __syncthreads();
    mm16(As, Bs, acc, tx, ty);
    __syncthreads();
  }
#pragma unroll
  for (int i = 0; i < 4; ++i)
#pragma unroll
    for (int j = 0; j < 4; ++j)
      x[(size_t)(row0 + ty * 4 + i) * Dd + n0 + tx * 4 + j] += ALPHA * acc[i][j];
}

// --------------------------------------------------------------------------
extern "C" void kernel_launch(void* const* d_in, const int* in_sizes, int n_in,
                              void* d_out, int out_size, void* d_ws, size_t ws_size,
                              hipStream_t stream) {
  const float* x_in  = (const float*)d_in[0];
  const float* Wq    = (const float*)d_in[1];
  const float* Wk    = (const float*)d_in[2];
  const float* xi    = (const float*)d_in[3];
  const float* gamma = (const float*)d_in[4];
  const float* delta = (const float*)d_in[5];
  float* x = (float*)d_out;

  const size_t SZ = (size_t)BN_TOT * HY;          // 3,145,728 floats
  float* g   = (float*)d_ws;
  float* q   = g + SZ;
  float* k   = q + SZ;
  float* dq  = k + SZ;
  float* dk  = dq + SZ;
  float* P   = dk + SZ;                           // per-batch [H,N,N] (= SZ floats)
  float* hid = P + SZ;                            // [4096, 3072]

  size_t need = (6 * SZ + (size_t)BN_TOT * Mm) * sizeof(float);
  if (ws_size < need) return;  // insufficient scratch; fail loudly via validation

  hipMemcpyAsync(x, x_in, SZ * sizeof(float), hipMemcpyDeviceToDevice, stream);

  for (int step = 0; step < 12; ++step) {
    k_ln<<<BN_TOT, 256, 0, stream>>>(x, gamma, delta, g);
    k_qkproj<<<dim3(HY / TILE, BN_TOT / TILE, 2), 256, 0, stream>>>(g, Wq, Wk, q, k);
    for (int b = 0; b < Bb; ++b) {
      const float* qb = q + (size_t)b * Nn * HY;
      const float* kb = k + (size_t)b * Nn * HY;
      k_scores<<<dim3(Nn / TILE, Nn / TILE, Hh), 256, 0, stream>>>(qb, kb, P);
      k_softmax<<<dim3(Nn, Hh), 256, 0, stream>>>(P);
      k_dq<<<dim3(1, Nn / TILE, Hh), 256, 0, stream>>>(P, kb, dq + (size_t)b * Nn * HY);
      k_dk<<<dim3(1, Nn / TILE, Hh), 256, 0, stream>>>(P, qb, dk + (size_t)b * Nn * HY);
    }
    k_upd2<<<dim3(Dd / TILE, BN_TOT / TILE), 256, 0, stream>>>(dq, dk, Wq, Wk, x);
    k_hid<<<dim3(Mm / TILE, BN_TOT / TILE), 256, 0, stream>>>(g, xi, hid);
    k_updhid<<<dim3(Dd / TILE, BN_TOT / TILE), 256, 0, stream>>>(hid, xi, x);
  }
}

// Round 4
// 4085.192 us; speedup vs baseline: 5.8756x; 5.8756x over previous
//
#include <hip/hip_runtime.h>

typedef _Float16 f16;
typedef __attribute__((ext_vector_type(8))) _Float16 half8;
typedef __attribute__((ext_vector_type(4))) _Float16 half4;
typedef __attribute__((ext_vector_type(4))) float f32x4;

#define Bb 8
#define Nn 512
#define Dd 768
#define Hh 12
#define Yy 64
#define Mm 3072
#define BN_TOT (Bb*Nn)   /* 4096 */
#define HY (Hh*Yy)       /* 768 */
#define ALPHA 0.1f
#define BETA 0.125f
#define LN_EPS 1e-5f

// ---------------------------------------------------------------- LayerNorm -> f16 g
__global__ __launch_bounds__(256) void k_ln(const float* __restrict__ x,
                                            const float* __restrict__ gamma,
                                            const float* __restrict__ delta,
                                            f16* __restrict__ g) {
  int row = blockIdx.x;
  const float* xr = x + (size_t)row * Dd;
  f16* gr = g + (size_t)row * Dd;
  int t = threadIdx.x;
  float v0 = xr[t], v1 = xr[t + 256], v2 = xr[t + 512];
  float s = v0 + v1 + v2;
  float ss = v0 * v0 + v1 * v1 + v2 * v2;
#pragma unroll
  for (int o = 32; o; o >>= 1) {
    s += __shfl_xor(s, o);
    ss += __shfl_xor(ss, o);
  }
  __shared__ float red[8];
  int wave = t >> 6;
  if ((t & 63) == 0) { red[wave] = s; red[4 + wave] = ss; }
  __syncthreads();
  float ts = red[0] + red[1] + red[2] + red[3];
  float tss = red[4] + red[5] + red[6] + red[7];
  float mu = ts * (1.0f / Dd);
  float var = tss * (1.0f / Dd) - mu * mu;
  float rstd = rsqrtf(var + LN_EPS);
  gr[t]       = (f16)(gamma[t]       * (v0 - mu) * rstd + delta[t]);
  gr[t + 256] = (f16)(gamma[t + 256] * (v1 - mu) * rstd + delta[t + 256]);
  gr[t + 512] = (f16)(gamma[t + 512] * (v2 - mu) * rstd + delta[t + 512]);
}

// ---------------------------------------- fp32 [R][C] -> f16 copy + f16 transpose
__global__ __launch_bounds__(256) void k_cvt_tr(const float* __restrict__ in, int R, int C,
                                                f16* __restrict__ outB, f16* __restrict__ outT) {
  __shared__ float tile[64][65];
  int r0 = blockIdx.y * 64, c0 = blockIdx.x * 64;
  int tid = threadIdx.x;
#pragma unroll
  for (int e = 0; e < 16; ++e) {
    int idx = e * 256 + tid;
    int r = idx >> 6, c = idx & 63;
    float v = in[(size_t)(r0 + r) * C + c0 + c];
    tile[r][c] = v;
    outB[(size_t)(r0 + r) * C + c0 + c] = (f16)v;
  }
  __syncthreads();
#pragma unroll
  for (int e = 0; e < 16; ++e) {
    int idx = e * 256 + tid;
    int rr = idx >> 6, c = idx & 63;
    outT[(size_t)(c0 + rr) * R + r0 + c] = (f16)tile[c][rr];
  }
}

// ------------------------------------------------------------ MFMA GEMM core
// C[M][N] += A[M][lda] * Bt[N][ldb]^T, both f16 with K on the fast axis.
__device__ __forceinline__ int swz(int r, int c) { return c ^ ((r ^ (r >> 2)) & 3); }

template<int FM, int FN>
__device__ __forceinline__ void zacc(f32x4 (&a)[FM][FN]) {
  f32x4 z = {0.f, 0.f, 0.f, 0.f};
#pragma unroll
  for (int i = 0; i < FM; ++i)
#pragma unroll
    for (int j = 0; j < FN; ++j) a[i][j] = z;
}

template<int BM, int BN, int WM, int WN>
__device__ __forceinline__ void gemm_core(const f16* __restrict__ A, int lda, int row0,
                                          const f16* __restrict__ Bt, int ldb, int col0,
                                          int K,
                                          f32x4 (&acc)[BM / WM / 16][BN / WN / 16],
                                          half8* sA, half8* sB) {
  constexpr int FM = BM / WM / 16, FN = BN / WN / 16;
  const int tid = threadIdx.x;
  const int w = tid >> 6, lane = tid & 63;
  const int wm = (WN == 1) ? w : (w >> 1);
  const int wn = (WN == 1) ? 0 : (w & 1);
  const int m0 = wm * (BM / WM), n0 = wn * (BN / WN);
  const int lr = lane & 15, lk = lane >> 4;
  for (int k0 = 0; k0 < K; k0 += 32) {
#pragma unroll
    for (int c = tid; c < BM * 4; c += 256) {
      int r = c >> 2, cc = c & 3;
      sA[r * 4 + swz(r, cc)] = *(const half8*)(A + (size_t)(row0 + r) * lda + k0 + cc * 8);
    }
#pragma unroll
    for (int c = tid; c < BN * 4; c += 256) {
      int r = c >> 2, cc = c & 3;
      sB[r * 4 + swz(r, cc)] = *(const half8*)(Bt + (size_t)(col0 + r) * ldb + k0 + cc * 8);
    }
    __syncthreads();
    half8 af[FM], bfr[FN];
#pragma unroll
    for (int i = 0; i < FM; ++i) { int r = m0 + i * 16 + lr; af[i] = sA[r * 4 + swz(r, lk)]; }
#pragma unroll
    for (int j = 0; j < FN; ++j) { int r = n0 + j * 16 + lr; bfr[j] = sB[r * 4 + swz(r, lk)]; }
#pragma unroll
    for (int i = 0; i < FM; ++i)
#pragma unroll
      for (int j = 0; j < FN; ++j)
        acc[i][j] = __builtin_amdgcn_mfma_f32_16x16x32_f16(af[i], bfr[j], acc[i][j], 0, 0, 0);
    __syncthreads();
  }
}

// ---------------------------------------------------- q/k projection + transposed copies
__global__ __launch_bounds__(256) void k_qkproj(const f16* __restrict__ g,
                                                const f16* __restrict__ Wqh,
                                                const f16* __restrict__ Wkh,
                                                f16* __restrict__ q, f16* __restrict__ k,
                                                f16* __restrict__ qT, f16* __restrict__ kT) {
  __shared__ half8 sA[512], sB[512];
  const f16* Wh = blockIdx.z ? Wkh : Wqh;
  f16* out = blockIdx.z ? k : q;
  f16* outT = blockIdx.z ? kT : qT;
  int row0 = blockIdx.y * 128, col0 = blockIdx.x * 128;
  f32x4 acc[4][4];
  zacc(acc);
  gemm_core<128, 128, 2, 2>(g, Dd, row0, Wh, Dd, col0, Dd, acc, sA, sB);
  int w = threadIdx.x >> 6, lane = threadIdx.x & 63;
  int m0 = (w >> 1) * 64, n0 = (w & 1) * 64, lr = lane & 15, lk = lane >> 4;
#pragma unroll
  for (int i = 0; i < 4; ++i)
#pragma unroll
    for (int j = 0; j < 4; ++j) {
      int r0g = row0 + m0 + i * 16 + lk * 4;
      int cg = col0 + n0 + j * 16 + lr;
      half4 hv;
#pragma unroll
      for (int p = 0; p < 4; ++p) {
        f16 h1 = (f16)acc[i][j][p];
        out[(size_t)(r0g + p) * HY + cg] = h1;
        hv[p] = h1;
      }
      int b = r0g >> 9, nl = r0g & 511;
      int h = cg >> 6, y = cg & 63;
      *(half4*)(outT + (((size_t)b * Hh + h) * Yy + y) * Nn + nl) = hv;
    }
}

// -------------------------------------------------------- scores S = beta * q k^T
__global__ __launch_bounds__(256) void k_scores(const f16* __restrict__ q,
                                                const f16* __restrict__ k,
                                                f16* __restrict__ SP, int zbase) {
  __shared__ half8 sA[512], sB[512];
  int zg = zbase + blockIdx.z;
  int b = zg / Hh, h = zg - b * Hh;
  const f16* A = q + (size_t)b * Nn * HY + h * Yy;
  const f16* Bt = k + (size_t)b * Nn * HY + h * Yy;
  int row0 = blockIdx.y * 128, col0 = blockIdx.x * 128;
  f32x4 acc[4][4];
  zacc(acc);
  gemm_core<128, 128, 2, 2>(A, HY, row0, Bt, HY, col0, Yy, acc, sA, sB);
  f16* S = SP + (size_t)blockIdx.z * Nn * Nn;
  int w = threadIdx.x >> 6, lane = threadIdx.x & 63;
  int m0 = (w >> 1) * 64, n0 = (w & 1) * 64, lr = lane & 15, lk = lane >> 4;
#pragma unroll
  for (int i = 0; i < 4; ++i)
#pragma unroll
    for (int j = 0; j < 4; ++j) {
      int r0g = row0 + m0 + i * 16 + lk * 4;
      int cg = col0 + n0 + j * 16 + lr;
#pragma unroll
      for (int p = 0; p < 4; ++p)
        S[(size_t)(r0g + p) * Nn + cg] = (f16)(BETA * acc[i][j][p]);
    }
}

// ------------------------------------------------------------- row softmax (in-place f16)
__global__ __launch_bounds__(256) void k_softmax(f16* __restrict__ SP) {
  f16* row = SP + ((size_t)blockIdx.y * Nn + blockIdx.x) * Nn;
  int t = threadIdx.x;
  float a = (float)row[t], b = (float)row[t + 256];
  float mx = fmaxf(a, b);
#pragma unroll
  for (int o = 32; o; o >>= 1) mx = fmaxf(mx, __shfl_xor(mx, o));
  __shared__ float rm[4], rs[4];
  int wave = t >> 6;
  if ((t & 63) == 0) rm[wave] = mx;
  __syncthreads();
  mx = fmaxf(fmaxf(rm[0], rm[1]), fmaxf(rm[2], rm[3]));
  float ea = __expf(a - mx), eb = __expf(b - mx);
  float s = ea + eb;
#pragma unroll
  for (int o = 32; o; o >>= 1) s += __shfl_xor(s, o);
  if ((t & 63) == 0) rs[wave] = s;
  __syncthreads();
  float inv = 1.0f / (rs[0] + rs[1] + rs[2] + rs[3]);
  row[t] = (f16)(ea * inv);
  row[t + 256] = (f16)(eb * inv);
}

// ------------------------------------------------------------- P -> P^T (per z)
__global__ __launch_bounds__(256) void k_transP(const f16* __restrict__ SP, f16* __restrict__ PT) {
  __shared__ f16 tile[64][72];
  const f16* P = SP + (size_t)blockIdx.z * Nn * Nn;
  f16* T = PT + (size_t)blockIdx.z * Nn * Nn;
  int nb = blockIdx.y * 64, mb = blockIdx.x * 64;
  int tid = threadIdx.x;
#pragma unroll
  for (int e = 0; e < 2; ++e) {
    int ci = e * 256 + tid;
    int r = ci >> 3, c = (ci & 7) * 8;
    half8 v = *(const half8*)(P + (size_t)(nb + r) * Nn + mb + c);
#pragma unroll
    for (int qq = 0; qq < 8; ++qq) tile[r][c + qq] = v[qq];
  }
  __syncthreads();
#pragma unroll
  for (int e = 0; e < 2; ++e) {
    int ci = e * 256 + tid;
    int r = ci >> 3, c = (ci & 7) * 8;
    half8 v;
#pragma unroll
    for (int qq = 0; qq < 8; ++qq) v[qq] = tile[c + qq][r];
    *(half8*)(T + (size_t)(mb + r) * Nn + nb + c) = v;
  }
}

// ------------------------------------------------------------ dq = P*K  (N=64)
__global__ __launch_bounds__(256) void k_dq(const f16* __restrict__ SP,
                                            const f16* __restrict__ kT,
                                            f16* __restrict__ dq, int zbase) {
  __shared__ half8 sA[512], sB[256];
  int zg = zbase + blockIdx.z;
  int b = zg / Hh, h = zg - b * Hh;
  const f16* A = SP + (size_t)blockIdx.z * Nn * Nn;
  const f16* Bt = kT + (size_t)zg * Yy * Nn;
  int row0 = blockIdx.y * 128;
  f32x4 acc[2][4];
  zacc(acc);
  gemm_core<128, 64, 4, 1>(A, Nn, row0, Bt, Nn, 0, Nn, acc, sA, sB);
  int w = threadIdx.x >> 6, lane = threadIdx.x & 63;
  int m0 = w * 32, lr = lane & 15, lk = lane >> 4;
#pragma unroll
  for (int i = 0; i < 2; ++i)
#pragma unroll
    for (int j = 0; j < 4; ++j) {
      int r0g = row0 + m0 + i * 16 + lk * 4;
      int cg = j * 16 + lr;
#pragma unroll
      for (int p = 0; p < 4; ++p)
        dq[(size_t)(b * Nn + r0g + p) * HY + h * Yy + cg] = (f16)acc[i][j][p];
    }
}

// ------------------------------------------------------------ dk = P^T*Q  (N=64)
__global__ __launch_bounds__(256) void k_dk(const f16* __restrict__ PT,
                                            const f16* __restrict__ qT,
                                            f16* __restrict__ dk, int zbase) {
  __shared__ half8 sA[512], sB[256];
  int zg = zbase + blockIdx.z;
  int b = zg / Hh, h = zg - b * Hh;
  const f16* A = PT + (size_t)blockIdx.z * Nn * Nn;
  const f16* Bt = qT + (size_t)zg * Yy * Nn;
  int row0 = blockIdx.y * 128;
  f32x4 acc[2][4];
  zacc(acc);
  gemm_core<128, 64, 4, 1>(A, Nn, row0, Bt, Nn, 0, Nn, acc, sA, sB);
  int w = threadIdx.x >> 6, lane = threadIdx.x & 63;
  int m0 = w * 32, lr = lane & 15, lk = lane >> 4;
#pragma unroll
  for (int i = 0; i < 2; ++i)
#pragma unroll
    for (int j = 0; j < 4; ++j) {
      int r0g = row0 + m0 + i * 16 + lk * 4;
      int cg = j * 16 + lr;
#pragma unroll
      for (int p = 0; p < 4; ++p)
        dk[(size_t)(b * Nn + r0g + p) * HY + h * Yy + cg] = (f16)acc[i][j][p];
    }
}

// ---------------------------------------- x += alpha*(dq Wq + dk Wk)
__global__ __launch_bounds__(256) void k_upd2(const f16* __restrict__ dq, const f16* __restrict__ WqT,
                                              const f16* __restrict__ dk, const f16* __restrict__ WkT,
                                              float* __restrict__ x) {
  __shared__ half8 sA[512], sB[512];
  int row0 = blockIdx.y * 128, col0 = blockIdx.x * 128;
  f32x4 acc[4][4];
  zacc(acc);
  gemm_core<128, 128, 2, 2>(dq, HY, row0, WqT, HY, col0, HY, acc, sA, sB);
  gemm_core<128, 128, 2, 2>(dk, HY, row0, WkT, HY, col0, HY, acc, sA, sB);
  int w = threadIdx.x >> 6, lane = threadIdx.x & 63;
  int m0 = (w >> 1) * 64, n0 = (w & 1) * 64, lr = lane & 15, lk = lane >> 4;
#pragma unroll
  for (int i = 0; i < 4; ++i)
#pragma unroll
    for (int j = 0; j < 4; ++j) {
      int r0g = row0 + m0 + i * 16 + lk * 4;
      int cg = col0 + n0 + j * 16 + lr;
#pragma unroll
      for (int p = 0; p < 4; ++p)
        x[(size_t)(r0g + p) * Dd + cg] += ALPHA * acc[i][j][p];
    }
}

// ----------------------------------------------- hid = relu(g xi^T)
__global__ __launch_bounds__(256) void k_hid(const f16* __restrict__ g, const f16* __restrict__ xih,
                                             f16* __restrict__ hid) {
  __shared__ half8 sA[512], sB[512];
  int row0 = blockIdx.y * 128, col0 = blockIdx.x * 128;
  f32x4 acc[4][4];
  zacc(acc);
  gemm_core<128, 128, 2, 2>(g, Dd, row0, xih, Dd, col0, Dd, acc, sA, sB);
  int w = threadIdx.x >> 6, lane = threadIdx.x & 63;
  int m0 = (w >> 1) * 64, n0 = (w & 1) * 64, lr = lane & 15, lk = lane >> 4;
#pragma unroll
  for (int i = 0; i < 4; ++i)
#pragma unroll
    for (int j = 0; j < 4; ++j) {
      int r0g = row0 + m0 + i * 16 + lk * 4;
      int cg = col0 + n0 + j * 16 + lr;
#pragma unroll
      for (int p = 0; p < 4; ++p)
        hid[(size_t)(r0g + p) * Mm + cg] = (f16)fmaxf(acc[i][j][p], 0.0f);
    }
}

// ----------------------------------------------- x += alpha * hid xi
__global__ __launch_bounds__(256) void k_updhid(const f16* __restrict__ hid, const f16* __restrict__ xiT,
                                                float* __restrict__ x) {
  __shared__ half8 sA[512], sB[512];
  int row0 = blockIdx.y * 128, col0 = blockIdx.x * 128;
  f32x4 acc[4][4];
  zacc(acc);
  gemm_core<128, 128, 2, 2>(hid, Mm, row0, xiT, Mm, col0, Mm, acc, sA, sB);
  int w = threadIdx.x >> 6, lane = threadIdx.x & 63;
  int m0 = (w >> 1) * 64, n0 = (w & 1) * 64, lr = lane & 15, lk = lane >> 4;
#pragma unroll
  for (int i = 0; i < 4; ++i)
#pragma unroll
    for (int j = 0; j < 4; ++j) {
      int r0g = row0 + m0 + i * 16 + lk * 4;
      int cg = col0 + n0 + j * 16 + lr;
#pragma unroll
      for (int p = 0; p < 4; ++p)
        x[(size_t)(r0g + p) * Dd + cg] += ALPHA * acc[i][j][p];
    }
}

// --------------------------------------------------------------------------
extern "C" void kernel_launch(void* const* d_in, const int* in_sizes, int n_in,
                              void* d_out, int out_size, void* d_ws, size_t ws_size,
                              hipStream_t stream) {
  const float* x_in  = (const float*)d_in[0];
  const float* Wq    = (const float*)d_in[1];
  const float* Wk    = (const float*)d_in[2];
  const float* xi    = (const float*)d_in[3];
  const float* gamma = (const float*)d_in[4];
  const float* delta = (const float*)d_in[5];
  float* x = (float*)d_out;

  // ---- workspace carve (f16 buffers, 256B aligned)
  char* p = (char*)d_ws;
  size_t used = 0;
  auto alloc = [&](size_t elems) -> f16* {
    size_t bytes = (elems * sizeof(f16) + 255) & ~(size_t)255;
    f16* r = (f16*)(p + used);
    used += bytes;
    return r;
  };
  const size_t SZ = (size_t)BN_TOT * HY;       // 3,145,728
  f16* g   = alloc(SZ);
  f16* q   = alloc(SZ);
  f16* k   = alloc(SZ);
  f16* qT  = alloc(SZ);
  f16* kT  = alloc(SZ);
  f16* dq  = alloc(SZ);
  f16* dk  = alloc(SZ);
  f16* Wqh = alloc((size_t)HY * Dd);
  f16* Wkh = alloc((size_t)HY * Dd);
  f16* WqT = alloc((size_t)Dd * HY);
  f16* WkT = alloc((size_t)Dd * HY);
  f16* xih = alloc((size_t)Mm * Dd);
  f16* xiT = alloc((size_t)Dd * Mm);
  f16* SP  = alloc((size_t)48 * Nn * Nn);      // half-batch scores/P
  f16* PTH = alloc((size_t)48 * Nn * Nn);      // P^T, later reused as hid [4096][3072]
  f16* hid = PTH;                              // same element count: 48*512*512 == 4096*3072
  if (used > ws_size) return;

  hipMemcpyAsync(x, x_in, SZ * sizeof(float), hipMemcpyDeviceToDevice, stream);

  // one-time weight conversion + transposes
  k_cvt_tr<<<dim3(Dd / 64, HY / 64), 256, 0, stream>>>(Wq, HY, Dd, Wqh, WqT);
  k_cvt_tr<<<dim3(Dd / 64, HY / 64), 256, 0, stream>>>(Wk, HY, Dd, Wkh, WkT);
  k_cvt_tr<<<dim3(Dd / 64, Mm / 64), 256, 0, stream>>>(xi, Mm, Dd, xih, xiT);

  for (int step = 0; step < 12; ++step) {
    k_ln<<<BN_TOT, 256, 0, stream>>>(x, gamma, delta, g);
    k_qkproj<<<dim3(HY / 128, BN_TOT / 128, 2), 256, 0, stream>>>(g, Wqh, Wkh, q, k, qT, kT);
    for (int half = 0; half < 2; ++half) {
      int zbase = half * 48;
      k_scores<<<dim3(Nn / 128, Nn / 128, 48), 256, 0, stream>>>(q, k, SP, zbase);
      k_softmax<<<dim3(Nn, 48), 256, 0, stream>>>(SP);
      k_transP<<<dim3(8, 8, 48), 256, 0, stream>>>(SP, PTH);
      k_dq<<<dim3(1, Nn / 128, 48), 256, 0, stream>>>(SP, kT, dq, zbase);
      k_dk<<<dim3(1, Nn / 128, 48), 256, 0, stream>>>(PTH, qT, dk, zbase);
    }
    k_upd2<<<dim3(Dd / 128, BN_TOT / 128), 256, 0, stream>>>(dq, WqT, dk, WkT, x);
    k_hid<<<dim3(Mm / 128, BN_TOT / 128), 256, 0, stream>>>(g, xih, hid);
    k_updhid<<<dim3(Dd / 128, BN_TOT / 128), 256, 0, stream>>>(hid, xiT, x);
  }
}

// Round 6
// 3459.003 us; speedup vs baseline: 6.9393x; 1.1810x over previous
//
#include <hip/hip_runtime.h>

typedef _Float16 f16;
typedef __attribute__((ext_vector_type(8))) _Float16 half8;
typedef __attribute__((ext_vector_type(4))) _Float16 half4;
typedef __attribute__((ext_vector_type(4))) float f32x4;

#define Bb 8
#define Nn 512
#define Dd 768
#define Hh 12
#define Yy 64
#define Mm 3072
#define BN_TOT (Bb*Nn)   /* 4096 */
#define HY (Hh*Yy)       /* 768 */
#define ALPHA 0.1f
#define BETA 0.125f
#define LN_EPS 1e-5f

// ---------------------------------------------------------------- LayerNorm -> f16 g
__global__ __launch_bounds__(256) void k_ln(const float* __restrict__ x,
                                            const float* __restrict__ gamma,
                                            const float* __restrict__ delta,
                                            f16* __restrict__ g) {
  int row = blockIdx.x;
  const float* xr = x + (size_t)row * Dd;
  f16* gr = g + (size_t)row * Dd;
  int t = threadIdx.x;
  float v0 = xr[t], v1 = xr[t + 256], v2 = xr[t + 512];
  float s = v0 + v1 + v2;
  float ss = v0 * v0 + v1 * v1 + v2 * v2;
#pragma unroll
  for (int o = 32; o; o >>= 1) {
    s += __shfl_xor(s, o);
    ss += __shfl_xor(ss, o);
  }
  __shared__ float red[8];
  int wave = t >> 6;
  if ((t & 63) == 0) { red[wave] = s; red[4 + wave] = ss; }
  __syncthreads();
  float ts = red[0] + red[1] + red[2] + red[3];
  float tss = red[4] + red[5] + red[6] + red[7];
  float mu = ts * (1.0f / Dd);
  float var = tss * (1.0f / Dd) - mu * mu;
  float rstd = rsqrtf(var + LN_EPS);
  gr[t]       = (f16)(gamma[t]       * (v0 - mu) * rstd + delta[t]);
  gr[t + 256] = (f16)(gamma[t + 256] * (v1 - mu) * rstd + delta[t + 256]);
  gr[t + 512] = (f16)(gamma[t + 512] * (v2 - mu) * rstd + delta[t + 512]);
}

// ---------------------------------------- fp32 [R][C] -> f16 copy + f16 transpose
__global__ __launch_bounds__(256) void k_cvt_tr(const float* __restrict__ in, int R, int C,
                                                f16* __restrict__ outB, f16* __restrict__ outT) {
  __shared__ float tile[64][65];
  int r0 = blockIdx.y * 64, c0 = blockIdx.x * 64;
  int tid = threadIdx.x;
#pragma unroll
  for (int e = 0; e < 16; ++e) {
    int idx = e * 256 + tid;
    int r = idx >> 6, c = idx & 63;
    float v = in[(size_t)(r0 + r) * C + c0 + c];
    tile[r][c] = v;
    outB[(size_t)(r0 + r) * C + c0 + c] = (f16)v;
  }
  __syncthreads();
#pragma unroll
  for (int e = 0; e < 16; ++e) {
    int idx = e * 256 + tid;
    int rr = idx >> 6, c = idx & 63;
    outT[(size_t)(c0 + rr) * R + r0 + c] = (f16)tile[c][rr];
  }
}

// ------------------------------------------------------------ MFMA GEMM core
// C[M][N] += A[M][lda] * Bt[N][ldb]^T, both f16 with K on the fast axis.
// global_load_lds(16B) staging: LDS dest = wave-uniform base + lane*16 (linear
// [rows][32] f16 tile, 64 B/row => 4 lanes per row, 16 rows per wave-instr).
__device__ __forceinline__ void gl16(const f16* g, f16* l) {
  __builtin_amdgcn_global_load_lds(
      (const __attribute__((address_space(1))) void*)g,
      (__attribute__((address_space(3))) void*)l, 16, 0, 0);
}

template<int FM, int FN>
__device__ __forceinline__ void zacc(f32x4 (&a)[FM][FN]) {
  f32x4 z = {0.f, 0.f, 0.f, 0.f};
#pragma unroll
  for (int i = 0; i < FM; ++i)
#pragma unroll
    for (int j = 0; j < FN; ++j) a[i][j] = z;
}

template<int BM, int BN, int WM, int WN>
__device__ __forceinline__ void gemm_core(const f16* __restrict__ A, int lda, int row0,
                                          const f16* __restrict__ Bt, int ldb, int col0,
                                          int K,
                                          f32x4 (&acc)[BM / WM / 16][BN / WN / 16],
                                          f16* sA, f16* sB) {
  constexpr int FM = BM / WM / 16, FN = BN / WN / 16;
  const int tid = threadIdx.x;
  const int w = tid >> 6, lane = tid & 63;
  const int wm = (WN == 1) ? w : (w >> 1);
  const int wn = (WN == 1) ? 0 : (w & 1);
  const int m0 = wm * (BM / WM), n0 = wn * (BN / WN);
  const int lr = lane & 15, lk = lane >> 4;
  const int srow = lane >> 2;            // staging: lane -> row-within-16
  const int scol = (lane & 3) * 8;       // staging: lane -> k-chunk (8 halves)
  for (int k0 = 0; k0 < K; k0 += 32) {
#pragma unroll
    for (int t = 0; t < BM / 64; ++t) {  // wave w stages rows [w*BM/4 + t*16, +16)
      int r0 = w * (BM / 4) + t * 16;
      gl16(A + (size_t)(row0 + r0 + srow) * lda + k0 + scol, sA + r0 * 32);
    }
#pragma unroll
    for (int t = 0; t < BN / 64; ++t) {
      int r0 = w * (BN / 4) + t * 16;
      gl16(Bt + (size_t)(col0 + r0 + srow) * ldb + k0 + scol, sB + r0 * 32);
    }
    __syncthreads();                     // compiler drains vmcnt before barrier
    half8 af[FM], bfr[FN];
#pragma unroll
    for (int i = 0; i < FM; ++i)
      af[i] = *(const half8*)(sA + (m0 + i * 16 + lr) * 32 + lk * 8);
#pragma unroll
    for (int j = 0; j < FN; ++j)
      bfr[j] = *(const half8*)(sB + (n0 + j * 16 + lr) * 32 + lk * 8);
#pragma unroll
    for (int i = 0; i < FM; ++i)
#pragma unroll
      for (int j = 0; j < FN; ++j)
        acc[i][j] = __builtin_amdgcn_mfma_f32_16x16x32_f16(af[i], bfr[j], acc[i][j], 0, 0, 0);
    __syncthreads();
  }
}

// ---------------------------------------------------- q/k projection + transposed copies
__global__ __launch_bounds__(256) void k_qkproj(const f16* __restrict__ g,
                                                const f16* __restrict__ Wqh,
                                                const f16* __restrict__ Wkh,
                                                f16* __restrict__ q, f16* __restrict__ k,
                                                f16* __restrict__ qT, f16* __restrict__ kT) {
  __shared__ f16 sA[128 * 32], sB[128 * 32];
  const f16* Wh = blockIdx.z ? Wkh : Wqh;
  f16* out = blockIdx.z ? k : q;
  f16* outT = blockIdx.z ? kT : qT;
  int row0 = blockIdx.y * 128, col0 = blockIdx.x * 128;
  f32x4 acc[4][4];
  zacc(acc);
  gemm_core<128, 128, 2, 2>(g, Dd, row0, Wh, Dd, col0, Dd, acc, sA, sB);
  int w = threadIdx.x >> 6, lane = threadIdx.x & 63;
  int m0 = (w >> 1) * 64, n0 = (w & 1) * 64, lr = lane & 15, lk = lane >> 4;
#pragma unroll
  for (int i = 0; i < 4; ++i)
#pragma unroll
    for (int j = 0; j < 4; ++j) {
      int r0g = row0 + m0 + i * 16 + lk * 4;
      int cg = col0 + n0 + j * 16 + lr;
      half4 hv;
#pragma unroll
      for (int p = 0; p < 4; ++p) {
        f16 h1 = (f16)acc[i][j][p];
        out[(size_t)(r0g + p) * HY + cg] = h1;
        hv[p] = h1;
      }
      int b = r0g >> 9, nl = r0g & 511;
      int h = cg >> 6, y = cg & 63;
      *(half4*)(outT + (((size_t)b * Hh + h) * Yy + y) * Nn + nl) = hv;
    }
}

// -------------------------------------------------------- scores S = beta * q k^T
__global__ __launch_bounds__(256) void k_scores(const f16* __restrict__ q,
                                                const f16* __restrict__ k,
                                                f16* __restrict__ SP, int zbase) {
  __shared__ f16 sA[128 * 32], sB[128 * 32];
  int zg = zbase + blockIdx.z;
  int b = zg / Hh, h = zg - b * Hh;
  const f16* A = q + (size_t)b * Nn * HY + h * Yy;
  const f16* Bt = k + (size_t)b * Nn * HY + h * Yy;
  int row0 = blockIdx.y * 128, col0 = blockIdx.x * 128;
  f32x4 acc[4][4];
  zacc(acc);
  gemm_core<128, 128, 2, 2>(A, HY, row0, Bt, HY, col0, Yy, acc, sA, sB);
  f16* S = SP + (size_t)blockIdx.z * Nn * Nn;
  int w = threadIdx.x >> 6, lane = threadIdx.x & 63;
  int m0 = (w >> 1) * 64, n0 = (w & 1) * 64, lr = lane & 15, lk = lane >> 4;
#pragma unroll
  for (int i = 0; i < 4; ++i)
#pragma unroll
    for (int j = 0; j < 4; ++j) {
      int r0g = row0 + m0 + i * 16 + lk * 4;
      int cg = col0 + n0 + j * 16 + lr;
#pragma unroll
      for (int p = 0; p < 4; ++p)
        S[(size_t)(r0g + p) * Nn + cg] = (f16)(BETA * acc[i][j][p]);
    }
}

// ------------------------------------------------------------- row softmax (in-place f16)
__global__ __launch_bounds__(256) void k_softmax(f16* __restrict__ SP) {
  f16* row = SP + ((size_t)blockIdx.y * Nn + blockIdx.x) * Nn;
  int t = threadIdx.x;
  float a = (float)row[t], b = (float)row[t + 256];
  float mx = fmaxf(a, b);
#pragma unroll
  for (int o = 32; o; o >>= 1) mx = fmaxf(mx, __shfl_xor(mx, o));
  __shared__ float rm[4], rs[4];
  int wave = t >> 6;
  if ((t & 63) == 0) rm[wave] = mx;
  __syncthreads();
  mx = fmaxf(fmaxf(rm[0], rm[1]), fmaxf(rm[2], rm[3]));
  float ea = __expf(a - mx), eb = __expf(b - mx);
  float s = ea + eb;
#pragma unroll
  for (int o = 32; o; o >>= 1) s += __shfl_xor(s, o);
  if ((t & 63) == 0) rs[wave] = s;
  __syncthreads();
  float inv = 1.0f / (rs[0] + rs[1] + rs[2] + rs[3]);
  row[t] = (f16)(ea * inv);
  row[t + 256] = (f16)(eb * inv);
}

// ------------------------------------------------------------- P -> P^T (per z)
__global__ __launch_bounds__(256) void k_transP(const f16* __restrict__ SP, f16* __restrict__ PT) {
  __shared__ f16 tile[64][72];
  const f16* P = SP + (size_t)blockIdx.z * Nn * Nn;
  f16* T = PT + (size_t)blockIdx.z * Nn * Nn;
  int nb = blockIdx.y * 64, mb = blockIdx.x * 64;
  int tid = threadIdx.x;
#pragma unroll
  for (int e = 0; e < 2; ++e) {
    int ci = e * 256 + tid;
    int r = ci >> 3, c = (ci & 7) * 8;
    half8 v = *(const half8*)(P + (size_t)(nb + r) * Nn + mb + c);
#pragma unroll
    for (int qq = 0; qq < 8; ++qq) tile[r][c + qq] = v[qq];
  }
  __syncthreads();
#pragma unroll
  for (int e = 0; e < 2; ++e) {
    int ci = e * 256 + tid;
    int r = ci >> 3, c = (ci & 7) * 8;
    half8 v;
#pragma unroll
    for (int qq = 0; qq < 8; ++qq) v[qq] = tile[c + qq][r];
    *(half8*)(T + (size_t)(mb + r) * Nn + nb + c) = v;
  }
}

// --------------------------------------------- dq = P*K and dk = P^T*Q, one launch
// blockIdx.z: bit0 = which (0: dq from SP,kT; 1: dk from PT,qT), z>>1 = local z
__global__ __launch_bounds__(256) void k_dqdk(const f16* __restrict__ SP,
                                              const f16* __restrict__ PT,
                                              const f16* __restrict__ qT,
                                              const f16* __restrict__ kT,
                                              f16* __restrict__ dq,
                                              f16* __restrict__ dk, int zbase) {
  __shared__ f16 sA[128 * 32], sB[64 * 32];
  int which = blockIdx.z & 1, zloc = blockIdx.z >> 1;
  int zg = zbase + zloc;
  int b = zg / Hh, h = zg - b * Hh;
  const f16* A = (which ? PT : SP) + (size_t)zloc * Nn * Nn;
  const f16* Bt = (which ? qT : kT) + (size_t)zg * Yy * Nn;
  f16* out = which ? dk : dq;
  int row0 = blockIdx.y * 128;
  f32x4 acc[2][4];
  zacc(acc);
  gemm_core<128, 64, 4, 1>(A, Nn, row0, Bt, Nn, 0, Nn, acc, sA, sB);
  int w = threadIdx.x >> 6, lane = threadIdx.x & 63;
  int m0 = w * 32, lr = lane & 15, lk = lane >> 4;
#pragma unroll
  for (int i = 0; i < 2; ++i)
#pragma unroll
    for (int j = 0; j < 4; ++j) {
      int r0g = row0 + m0 + i * 16 + lk * 4;
      int cg = j * 16 + lr;
#pragma unroll
      for (int p = 0; p < 4; ++p)
        out[(size_t)(b * Nn + r0g + p) * HY + h * Yy + cg] = (f16)acc[i][j][p];
    }
}

// ------------------- x += alpha*(dq Wq + dk Wk), split over z = (K-half, src)
__global__ __launch_bounds__(256) void k_upd2(const f16* __restrict__ dq, const f16* __restrict__ WqT,
                                              const f16* __restrict__ dk, const f16* __restrict__ WkT,
                                              float* __restrict__ x) {
  __shared__ f16 sA[128 * 32], sB[128 * 32];
  int which = blockIdx.z & 1, khalf = blockIdx.z >> 1;
  const f16* A = (which ? dk : dq) + khalf * (HY / 2);
  const f16* Bt = (which ? WkT : WqT) + khalf * (HY / 2);
  int row0 = blockIdx.y * 128, col0 = blockIdx.x * 128;
  f32x4 acc[4][4];
  zacc(acc);
  gemm_core<128, 128, 2, 2>(A, HY, row0, Bt, HY, col0, HY / 2, acc, sA, sB);
  int w = threadIdx.x >> 6, lane = threadIdx.x & 63;
  int m0 = (w >> 1) * 64, n0 = (w & 1) * 64, lr = lane & 15, lk = lane >> 4;
#pragma unroll
  for (int i = 0; i < 4; ++i)
#pragma unroll
    for (int j = 0; j < 4; ++j) {
      int r0g = row0 + m0 + i * 16 + lk * 4;
      int cg = col0 + n0 + j * 16 + lr;
#pragma unroll
      for (int p = 0; p < 4; ++p)
        atomicAdd(&x[(size_t)(r0g + p) * Dd + cg], ALPHA * acc[i][j][p]);
    }
}

// ----------------------------------------------- hid = relu(g xi^T)
__global__ __launch_bounds__(256) void k_hid(const f16* __restrict__ g, const f16* __restrict__ xih,
                                             f16* __restrict__ hid) {
  __shared__ f16 sA[128 * 32], sB[128 * 32];
  int row0 = blockIdx.y * 128, col0 = blockIdx.x * 128;
  f32x4 acc[4][4];
  zacc(acc);
  gemm_core<128, 128, 2, 2>(g, Dd, row0, xih, Dd, col0, Dd, acc, sA, sB);
  int w = threadIdx.x >> 6, lane = threadIdx.x & 63;
  int m0 = (w >> 1) * 64, n0 = (w & 1) * 64, lr = lane & 15, lk = lane >> 4;
#pragma unroll
  for (int i = 0; i < 4; ++i)
#pragma unroll
    for (int j = 0; j < 4; ++j) {
      int r0g = row0 + m0 + i * 16 + lk * 4;
      int cg = col0 + n0 + j * 16 + lr;
#pragma unroll
      for (int p = 0; p < 4; ++p)
        hid[(size_t)(r0g + p) * Mm + cg] = (f16)fmaxf(acc[i][j][p], 0.0f);
    }
}

// ------------------- x += alpha * hid xi, split over z = K-quarter of Mm
__global__ __launch_bounds__(256) void k_updhid(const f16* __restrict__ hid, const f16* __restrict__ xiT,
                                                float* __restrict__ x) {
  __shared__ f16 sA[128 * 32], sB[128 * 32];
  int zq = blockIdx.z;
  const f16* A = hid + zq * (Mm / 4);
  const f16* Bt = xiT + zq * (Mm / 4);
  int row0 = blockIdx.y * 128, col0 = blockIdx.x * 128;
  f32x4 acc[4][4];
  zacc(acc);
  gemm_core<128, 128, 2, 2>(A, Mm, row0, Bt, Mm, col0, Mm / 4, acc, sA, sB);
  int w = threadIdx.x >> 6, lane = threadIdx.x & 63;
  int m0 = (w >> 1) * 64, n0 = (w & 1) * 64, lr = lane & 15, lk = lane >> 4;
#pragma unroll
  for (int i = 0; i < 4; ++i)
#pragma unroll
    for (int j = 0; j < 4; ++j) {
      int r0g = row0 + m0 + i * 16 + lk * 4;
      int cg = col0 + n0 + j * 16 + lr;
#pragma unroll
      for (int p = 0; p < 4; ++p)
        atomicAdd(&x[(size_t)(r0g + p) * Dd + cg], ALPHA * acc[i][j][p]);
    }
}

// --------------------------------------------------------------------------
extern "C" void kernel_launch(void* const* d_in, const int* in_sizes, int n_in,
                              void* d_out, int out_size, void* d_ws, size_t ws_size,
                              hipStream_t stream) {
  const float* x_in  = (const float*)d_in[0];
  const float* Wq    = (const float*)d_in[1];
  const float* Wk    = (const float*)d_in[2];
  const float* xi    = (const float*)d_in[3];
  const float* gamma = (const float*)d_in[4];
  const float* delta = (const float*)d_in[5];
  float* x = (float*)d_out;

  // ---- workspace carve (f16 buffers, 256B aligned)
  char* p = (char*)d_ws;
  size_t used = 0;
  auto alloc = [&](size_t elems) -> f16* {
    size_t bytes = (elems * sizeof(f16) + 255) & ~(size_t)255;
    f16* r = (f16*)(p + used);
    used += bytes;
    return r;
  };
  const size_t SZ = (size_t)BN_TOT * HY;       // 3,145,728
  f16* g   = alloc(SZ);
  f16* q   = alloc(SZ);
  f16* k   = alloc(SZ);
  f16* qT  = alloc(SZ);
  f16* kT  = alloc(SZ);
  f16* dq  = alloc(SZ);
  f16* dk  = alloc(SZ);
  f16* Wqh = alloc((size_t)HY * Dd);
  f16* Wkh = alloc((size_t)HY * Dd);
  f16* WqT = alloc((size_t)Dd * HY);
  f16* WkT = alloc((size_t)Dd * HY);
  f16* xih = alloc((size_t)Mm * Dd);
  f16* xiT = alloc((size_t)Dd * Mm);
  f16* SP  = alloc((size_t)48 * Nn * Nn);      // half-batch scores/P
  f16* PTH = alloc((size_t)48 * Nn * Nn);      // P^T, later reused as hid [4096][3072]
  f16* hid = PTH;                              // same element count: 48*512*512 == 4096*3072
  if (used > ws_size) return;

  hipMemcpyAsync(x, x_in, SZ * sizeof(float), hipMemcpyDeviceToDevice, stream);

  // one-time weight conversion + transposes
  k_cvt_tr<<<dim3(Dd / 64, HY / 64), 256, 0, stream>>>(Wq, HY, Dd, Wqh, WqT);
  k_cvt_tr<<<dim3(Dd / 64, HY / 64), 256, 0, stream>>>(Wk, HY, Dd, Wkh, WkT);
  k_cvt_tr<<<dim3(Dd / 64, Mm / 64), 256, 0, stream>>>(xi, Mm, Dd, xih, xiT);

  for (int step = 0; step < 12; ++step) {
    k_ln<<<BN_TOT, 256, 0, stream>>>(x, gamma, delta, g);
    k_qkproj<<<dim3(HY / 128, BN_TOT / 128, 2), 256, 0, stream>>>(g, Wqh, Wkh, q, k, qT, kT);
    for (int half = 0; half < 2; ++half) {
      int zbase = half * 48;
      k_scores<<<dim3(Nn / 128, Nn / 128, 48), 256, 0, stream>>>(q, k, SP, zbase);
      k_softmax<<<dim3(Nn, 48), 256, 0, stream>>>(SP);
      k_transP<<<dim3(8, 8, 48), 256, 0, stream>>>(SP, PTH);
      k_dqdk<<<dim3(1, Nn / 128, 96), 256, 0, stream>>>(SP, PTH, qT, kT, dq, dk, zbase);
    }
    k_upd2<<<dim3(Dd / 128, BN_TOT / 128, 4), 256, 0, stream>>>(dq, WqT, dk, WkT, x);
    k_hid<<<dim3(Mm / 128, BN_TOT / 128), 256, 0, stream>>>(g, xih, hid);
    k_updhid<<<dim3(Dd / 128, BN_TOT / 128, 4), 256, 0, stream>>>(hid, xiT, x);
  }
}

// Round 7
// 3116.268 us; speedup vs baseline: 7.7025x; 1.1100x over previous
//
#include <hip/hip_runtime.h>

typedef _Float16 f16;
typedef __attribute__((ext_vector_type(8))) _Float16 half8;
typedef __attribute__((ext_vector_type(4))) _Float16 half4;
typedef __attribute__((ext_vector_type(4))) float f32x4;

#define Bb 8
#define Nn 512
#define Dd 768
#define Hh 12
#define Yy 64
#define Mm 3072
#define BN_TOT (Bb*Nn)   /* 4096 */
#define HY (Hh*Yy)       /* 768 */
#define ALPHA 0.1f
#define BETA 0.125f
#define LN_EPS 1e-5f

// ---------------------------------------------------------------- LayerNorm -> f16 g
__global__ __launch_bounds__(256) void k_ln(const float* __restrict__ x,
                                            const float* __restrict__ gamma,
                                            const float* __restrict__ delta,
                                            f16* __restrict__ g) {
  int row = blockIdx.x;
  const float* xr = x + (size_t)row * Dd;
  f16* gr = g + (size_t)row * Dd;
  int t = threadIdx.x;
  float v0 = xr[t], v1 = xr[t + 256], v2 = xr[t + 512];
  float s = v0 + v1 + v2;
  float ss = v0 * v0 + v1 * v1 + v2 * v2;
#pragma unroll
  for (int o = 32; o; o >>= 1) {
    s += __shfl_xor(s, o);
    ss += __shfl_xor(ss, o);
  }
  __shared__ float red[8];
  int wave = t >> 6;
  if ((t & 63) == 0) { red[wave] = s; red[4 + wave] = ss; }
  __syncthreads();
  float ts = red[0] + red[1] + red[2] + red[3];
  float tss = red[4] + red[5] + red[6] + red[7];
  float mu = ts * (1.0f / Dd);
  float var = tss * (1.0f / Dd) - mu * mu;
  float rstd = rsqrtf(var + LN_EPS);
  gr[t]       = (f16)(gamma[t]       * (v0 - mu) * rstd + delta[t]);
  gr[t + 256] = (f16)(gamma[t + 256] * (v1 - mu) * rstd + delta[t + 256]);
  gr[t + 512] = (f16)(gamma[t + 512] * (v2 - mu) * rstd + delta[t + 512]);
}

// ---------------------------------------- fp32 [R][C] -> f16 copy + f16 transpose
__global__ __launch_bounds__(256) void k_cvt_tr(const float* __restrict__ in, int R, int C,
                                                f16* __restrict__ outB, f16* __restrict__ outT) {
  __shared__ float tile[64][65];
  int r0 = blockIdx.y * 64, c0 = blockIdx.x * 64;
  int tid = threadIdx.x;
#pragma unroll
  for (int e = 0; e < 16; ++e) {
    int idx = e * 256 + tid;
    int r = idx >> 6, c = idx & 63;
    float v = in[(size_t)(r0 + r) * C + c0 + c];
    tile[r][c] = v;
    outB[(size_t)(r0 + r) * C + c0 + c] = (f16)v;
  }
  __syncthreads();
#pragma unroll
  for (int e = 0; e < 16; ++e) {
    int idx = e * 256 + tid;
    int rr = idx >> 6, c = idx & 63;
    outT[(size_t)(c0 + rr) * R + r0 + c] = (f16)tile[c][rr];
  }
}

// ------------------------------------------------------------ MFMA GEMM core
__device__ __forceinline__ void gl16(const f16* g, f16* l) {
  __builtin_amdgcn_global_load_lds(
      (const __attribute__((address_space(1))) void*)g,
      (__attribute__((address_space(3))) void*)l, 16, 0, 0);
}

template<int FM, int FN>
__device__ __forceinline__ void zacc(f32x4 (&a)[FM][FN]) {
  f32x4 z = {0.f, 0.f, 0.f, 0.f};
#pragma unroll
  for (int i = 0; i < FM; ++i)
#pragma unroll
    for (int j = 0; j < FN; ++j) a[i][j] = z;
}

template<int BM, int BN, int WM, int WN>
__device__ __forceinline__ void gemm_core(const f16* __restrict__ A, int lda, int row0,
                                          const f16* __restrict__ Bt, int ldb, int col0,
                                          int K,
                                          f32x4 (&acc)[BM / WM / 16][BN / WN / 16],
                                          f16* sA, f16* sB) {
  constexpr int FM = BM / WM / 16, FN = BN / WN / 16;
  const int tid = threadIdx.x;
  const int w = tid >> 6, lane = tid & 63;
  const int wm = (WN == 1) ? w : (w >> 1);
  const int wn = (WN == 1) ? 0 : (w & 1);
  const int m0 = wm * (BM / WM), n0 = wn * (BN / WN);
  const int lr = lane & 15, lk = lane >> 4;
  const int srow = lane >> 2;            // staging: lane -> row-within-16
  const int scol = (lane & 3) * 8;       // staging: lane -> k-chunk (8 halves)
  for (int k0 = 0; k0 < K; k0 += 32) {
#pragma unroll
    for (int t = 0; t < BM / 64; ++t) {  // wave w stages rows [w*BM/4 + t*16, +16)
      int r0 = w * (BM / 4) + t * 16;
      gl16(A + (size_t)(row0 + r0 + srow) * lda + k0 + scol, sA + r0 * 32);
    }
#pragma unroll
    for (int t = 0; t < BN / 64; ++t) {
      int r0 = w * (BN / 4) + t * 16;
      gl16(Bt + (size_t)(col0 + r0 + srow) * ldb + k0 + scol, sB + r0 * 32);
    }
    __syncthreads();                     // compiler drains vmcnt before barrier
    half8 af[FM], bfr[FN];
#pragma unroll
    for (int i = 0; i < FM; ++i)
      af[i] = *(const half8*)(sA + (m0 + i * 16 + lr) * 32 + lk * 8);
#pragma unroll
    for (int j = 0; j < FN; ++j)
      bfr[j] = *(const half8*)(sB + (n0 + j * 16 + lr) * 32 + lk * 8);
#pragma unroll
    for (int i = 0; i < FM; ++i)
#pragma unroll
      for (int j = 0; j < FN; ++j)
        acc[i][j] = __builtin_amdgcn_mfma_f32_16x16x32_f16(af[i], bfr[j], acc[i][j], 0, 0, 0);
    __syncthreads();
  }
}

// ---------------------------------------------------- q/k projection + transposed copies
// grid (6, 32, 2) = 384 blocks, XCD-swizzled (384/8=48, 48%8==0)
__global__ __launch_bounds__(256) void k_qkproj(const f16* __restrict__ g,
                                                const f16* __restrict__ Wqh,
                                                const f16* __restrict__ Wkh,
                                                f16* __restrict__ q, f16* __restrict__ k,
                                                f16* __restrict__ qT, f16* __restrict__ kT) {
  __shared__ f16 sA[128 * 32], sB[128 * 32];
  int lin = blockIdx.x + blockIdx.y * 6 + blockIdx.z * 192;
  int swz = (lin & 7) * 48 + (lin >> 3);
  int col0 = (swz % 6) * 128;
  int row0 = ((swz / 6) & 31) * 128;
  int zq = swz / 192;
  const f16* Wh = zq ? Wkh : Wqh;
  f16* out = zq ? k : q;
  f16* outT = zq ? kT : qT;
  f32x4 acc[4][4];
  zacc(acc);
  gemm_core<128, 128, 2, 2>(g, Dd, row0, Wh, Dd, col0, Dd, acc, sA, sB);
  int w = threadIdx.x >> 6, lane = threadIdx.x & 63;
  int m0 = (w >> 1) * 64, n0 = (w & 1) * 64, lr = lane & 15, lk = lane >> 4;
#pragma unroll
  for (int i = 0; i < 4; ++i)
#pragma unroll
    for (int j = 0; j < 4; ++j) {
      int r0g = row0 + m0 + i * 16 + lk * 4;
      int cg = col0 + n0 + j * 16 + lr;
      half4 hv;
#pragma unroll
      for (int p = 0; p < 4; ++p) {
        f16 h1 = (f16)acc[i][j][p];
        out[(size_t)(r0g + p) * HY + cg] = h1;
        hv[p] = h1;
      }
      int b = r0g >> 9, nl = r0g & 511;
      int h = cg >> 6, y = cg & 63;
      *(half4*)(outT + (((size_t)b * Hh + h) * Yy + y) * Nn + nl) = hv;
    }
}

// -------------------------------------------------------- scores S = beta * q k^T
__global__ __launch_bounds__(256) void k_scores(const f16* __restrict__ q,
                                                const f16* __restrict__ k,
                                                f16* __restrict__ SP, int zbase) {
  __shared__ f16 sA[128 * 32], sB[128 * 32];
  int zg = zbase + blockIdx.z;
  int b = zg / Hh, h = zg - b * Hh;
  const f16* A = q + (size_t)b * Nn * HY + h * Yy;
  const f16* Bt = k + (size_t)b * Nn * HY + h * Yy;
  int row0 = blockIdx.y * 128, col0 = blockIdx.x * 128;
  f32x4 acc[4][4];
  zacc(acc);
  gemm_core<128, 128, 2, 2>(A, HY, row0, Bt, HY, col0, Yy, acc, sA, sB);
  f16* S = SP + (size_t)blockIdx.z * Nn * Nn;
  int w = threadIdx.x >> 6, lane = threadIdx.x & 63;
  int m0 = (w >> 1) * 64, n0 = (w & 1) * 64, lr = lane & 15, lk = lane >> 4;
#pragma unroll
  for (int i = 0; i < 4; ++i)
#pragma unroll
    for (int j = 0; j < 4; ++j) {
      int r0g = row0 + m0 + i * 16 + lk * 4;
      int cg = col0 + n0 + j * 16 + lr;
#pragma unroll
      for (int p = 0; p < 4; ++p)
        S[(size_t)(r0g + p) * Nn + cg] = (f16)(BETA * acc[i][j][p]);
    }
}

// ------------------------------------------------------------- row softmax (in-place f16)
__global__ __launch_bounds__(256) void k_softmax(f16* __restrict__ SP) {
  f16* row = SP + ((size_t)blockIdx.y * Nn + blockIdx.x) * Nn;
  int t = threadIdx.x;
  float a = (float)row[t], b = (float)row[t + 256];
  float mx = fmaxf(a, b);
#pragma unroll
  for (int o = 32; o; o >>= 1) mx = fmaxf(mx, __shfl_xor(mx, o));
  __shared__ float rm[4], rs[4];
  int wave = t >> 6;
  if ((t & 63) == 0) rm[wave] = mx;
  __syncthreads();
  mx = fmaxf(fmaxf(rm[0], rm[1]), fmaxf(rm[2], rm[3]));
  float ea = __expf(a - mx), eb = __expf(b - mx);
  float s = ea + eb;
#pragma unroll
  for (int o = 32; o; o >>= 1) s += __shfl_xor(s, o);
  if ((t & 63) == 0) rs[wave] = s;
  __syncthreads();
  float inv = 1.0f / (rs[0] + rs[1] + rs[2] + rs[3]);
  row[t] = (f16)(ea * inv);
  row[t + 256] = (f16)(eb * inv);
}

// ------------------------------------------------------------- P -> P^T (per z)
__global__ __launch_bounds__(256) void k_transP(const f16* __restrict__ SP, f16* __restrict__ PT) {
  __shared__ f16 tile[64][72];
  const f16* P = SP + (size_t)blockIdx.z * Nn * Nn;
  f16* T = PT + (size_t)blockIdx.z * Nn * Nn;
  int nb = blockIdx.y * 64, mb = blockIdx.x * 64;
  int tid = threadIdx.x;
#pragma unroll
  for (int e = 0; e < 2; ++e) {
    int ci = e * 256 + tid;
    int r = ci >> 3, c = (ci & 7) * 8;
    half8 v = *(const half8*)(P + (size_t)(nb + r) * Nn + mb + c);
#pragma unroll
    for (int qq = 0; qq < 8; ++qq) tile[r][c + qq] = v[qq];
  }
  __syncthreads();
#pragma unroll
  for (int e = 0; e < 2; ++e) {
    int ci = e * 256 + tid;
    int r = ci >> 3, c = (ci & 7) * 8;
    half8 v;
#pragma unroll
    for (int qq = 0; qq < 8; ++qq) v[qq] = tile[c + qq][r];
    *(half8*)(T + (size_t)(mb + r) * Nn + nb + c) = v;
  }
}

// --------------------------------------------- dq = P*K and dk = P^T*Q, one launch
__global__ __launch_bounds__(256) void k_dqdk(const f16* __restrict__ SP,
                                              const f16* __restrict__ PT,
                                              const f16* __restrict__ qT,
                                              const f16* __restrict__ kT,
                                              f16* __restrict__ dq,
                                              f16* __restrict__ dk, int zbase) {
  __shared__ f16 sA[128 * 32], sB[64 * 32];
  int which = blockIdx.z & 1, zloc = blockIdx.z >> 1;
  int zg = zbase + zloc;
  int b = zg / Hh, h = zg - b * Hh;
  const f16* A = (which ? PT : SP) + (size_t)zloc * Nn * Nn;
  const f16* Bt = (which ? qT : kT) + (size_t)zg * Yy * Nn;
  f16* out = which ? dk : dq;
  int row0 = blockIdx.y * 128;
  f32x4 acc[2][4];
  zacc(acc);
  gemm_core<128, 64, 4, 1>(A, Nn, row0, Bt, Nn, 0, Nn, acc, sA, sB);
  int w = threadIdx.x >> 6, lane = threadIdx.x & 63;
  int m0 = w * 32, lr = lane & 15, lk = lane >> 4;
#pragma unroll
  for (int i = 0; i < 2; ++i)
#pragma unroll
    for (int j = 0; j < 4; ++j) {
      int r0g = row0 + m0 + i * 16 + lk * 4;
      int cg = j * 16 + lr;
#pragma unroll
      for (int p = 0; p < 4; ++p)
        out[(size_t)(b * Nn + r0g + p) * HY + h * Yy + cg] = (f16)acc[i][j][p];
    }
}

// ----------------- x += alpha*(dq Wq + dk Wk + hid xi), 6 uniform K=768 slices
// grid (6, 32, 6) = 1152 blocks, XCD-swizzled (1152/8=144, 144%8==0)
// z'=0: dq*WqT; z'=1: dk*WkT; z'=2..5: hid quarter * xiT quarter
__global__ __launch_bounds__(256) void k_update(const f16* __restrict__ dq,
                                                const f16* __restrict__ dk,
                                                const f16* __restrict__ WqT,
                                                const f16* __restrict__ WkT,
                                                const f16* __restrict__ hid,
                                                const f16* __restrict__ xiT,
                                                float* __restrict__ x) {
  __shared__ f16 sA[128 * 32], sB[128 * 32];
  int lin = blockIdx.x + blockIdx.y * 6 + blockIdx.z * 192;
  int swz = (lin & 7) * 144 + (lin >> 3);
  int col0 = (swz % 6) * 128;
  int row0 = ((swz / 6) & 31) * 128;
  int zz = swz / 192;
  const f16* A; const f16* Bt; int lda, ldb;
  if (zz == 0)      { A = dq; Bt = WqT; lda = HY; ldb = HY; }
  else if (zz == 1) { A = dk; Bt = WkT; lda = HY; ldb = HY; }
  else              { A = hid + (zz - 2) * 768; Bt = xiT + (zz - 2) * 768; lda = Mm; ldb = Mm; }
  f32x4 acc[4][4];
  zacc(acc);
  gemm_core<128, 128, 2, 2>(A, lda, row0, Bt, ldb, col0, 768, acc, sA, sB);
  int w = threadIdx.x >> 6, lane = threadIdx.x & 63;
  int m0 = (w >> 1) * 64, n0 = (w & 1) * 64, lr = lane & 15, lk = lane >> 4;
#pragma unroll
  for (int i = 0; i < 4; ++i)
#pragma unroll
    for (int j = 0; j < 4; ++j) {
      int r0g = row0 + m0 + i * 16 + lk * 4;
      int cg = col0 + n0 + j * 16 + lr;
#pragma unroll
      for (int p = 0; p < 4; ++p)
        atomicAdd(&x[(size_t)(r0g + p) * Dd + cg], ALPHA * acc[i][j][p]);
    }
}

// ----------------------------------------------- hid = relu(g xi^T)
// grid (24, 32) = 768 blocks, XCD-swizzled (768/8=96, 96%8==0)
__global__ __launch_bounds__(256) void k_hid(const f16* __restrict__ g, const f16* __restrict__ xih,
                                             f16* __restrict__ hid) {
  __shared__ f16 sA[128 * 32], sB[128 * 32];
  int lin = blockIdx.x + blockIdx.y * 24;
  int swz = (lin & 7) * 96 + (lin >> 3);
  int col0 = (swz % 24) * 128;
  int row0 = (swz / 24) * 128;
  f32x4 acc[4][4];
  zacc(acc);
  gemm_core<128, 128, 2, 2>(g, Dd, row0, xih, Dd, col0, Dd, acc, sA, sB);
  int w = threadIdx.x >> 6, lane = threadIdx.x & 63;
  int m0 = (w >> 1) * 64, n0 = (w & 1) * 64, lr = lane & 15, lk = lane >> 4;
#pragma unroll
  for (int i = 0; i < 4; ++i)
#pragma unroll
    for (int j = 0; j < 4; ++j) {
      int r0g = row0 + m0 + i * 16 + lk * 4;
      int cg = col0 + n0 + j * 16 + lr;
#pragma unroll
      for (int p = 0; p < 4; ++p)
        hid[(size_t)(r0g + p) * Mm + cg] = (f16)fmaxf(acc[i][j][p], 0.0f);
    }
}

// --------------------------------------------------------------------------
extern "C" void kernel_launch(void* const* d_in, const int* in_sizes, int n_in,
                              void* d_out, int out_size, void* d_ws, size_t ws_size,
                              hipStream_t stream) {
  const float* x_in  = (const float*)d_in[0];
  const float* Wq    = (const float*)d_in[1];
  const float* Wk    = (const float*)d_in[2];
  const float* xi    = (const float*)d_in[3];
  const float* gamma = (const float*)d_in[4];
  const float* delta = (const float*)d_in[5];
  float* x = (float*)d_out;

  // ---- workspace carve (f16 buffers, 256B aligned)
  char* p = (char*)d_ws;
  size_t used = 0;
  auto alloc = [&](size_t elems) -> f16* {
    size_t bytes = (elems * sizeof(f16) + 255) & ~(size_t)255;
    f16* r = (f16*)(p + used);
    used += bytes;
    return r;
  };
  const size_t SZ = (size_t)BN_TOT * HY;       // 3,145,728
  f16* g   = alloc(SZ);
  f16* q   = alloc(SZ);
  f16* k   = alloc(SZ);
  f16* qT  = alloc(SZ);
  f16* kT  = alloc(SZ);
  f16* dq  = alloc(SZ);
  f16* dk  = alloc(SZ);
  f16* Wqh = alloc((size_t)HY * Dd);
  f16* Wkh = alloc((size_t)HY * Dd);
  f16* WqT = alloc((size_t)Dd * HY);
  f16* WkT = alloc((size_t)Dd * HY);
  f16* xih = alloc((size_t)Mm * Dd);
  f16* xiT = alloc((size_t)Dd * Mm);
  f16* SP  = alloc((size_t)48 * Nn * Nn);      // half-batch scores/P
  f16* PTH = alloc((size_t)48 * Nn * Nn);      // P^T, later reused as hid [4096][3072]
  f16* hid = PTH;                              // same element count: 48*512*512 == 4096*3072
  if (used > ws_size) return;

  hipMemcpyAsync(x, x_in, SZ * sizeof(float), hipMemcpyDeviceToDevice, stream);

  // one-time weight conversion + transposes
  k_cvt_tr<<<dim3(Dd / 64, HY / 64), 256, 0, stream>>>(Wq, HY, Dd, Wqh, WqT);
  k_cvt_tr<<<dim3(Dd / 64, HY / 64), 256, 0, stream>>>(Wk, HY, Dd, Wkh, WkT);
  k_cvt_tr<<<dim3(Dd / 64, Mm / 64), 256, 0, stream>>>(xi, Mm, Dd, xih, xiT);

  for (int step = 0; step < 12; ++step) {
    k_ln<<<BN_TOT, 256, 0, stream>>>(x, gamma, delta, g);
    k_qkproj<<<dim3(6, 32, 2), 256, 0, stream>>>(g, Wqh, Wkh, q, k, qT, kT);
    for (int half = 0; half < 2; ++half) {
      int zbase = half * 48;
      k_scores<<<dim3(Nn / 128, Nn / 128, 48), 256, 0, stream>>>(q, k, SP, zbase);
      k_softmax<<<dim3(Nn, 48), 256, 0, stream>>>(SP);
      k_transP<<<dim3(8, 8, 48), 256, 0, stream>>>(SP, PTH);
      k_dqdk<<<dim3(1, Nn / 128, 96), 256, 0, stream>>>(SP, PTH, qT, kT, dq, dk, zbase);
    }
    k_hid<<<dim3(24, 32), 256, 0, stream>>>(g, xih, hid);
    k_update<<<dim3(6, 32, 6), 256, 0, stream>>>(dq, dk, WqT, WkT, hid, xiT, x);
  }
}

// Round 8
// 2670.894 us; speedup vs baseline: 8.9869x; 1.1668x over previous
//
#include <hip/hip_runtime.h>

typedef _Float16 f16;
typedef __attribute__((ext_vector_type(8))) _Float16 half8;
typedef __attribute__((ext_vector_type(4))) _Float16 half4;
typedef __attribute__((ext_vector_type(4))) float f32x4;

#define Bb 8
#define Nn 512
#define Dd 768
#define Hh 12
#define Yy 64
#define Mm 3072
#define BN_TOT (Bb*Nn)   /* 4096 */
#define HY (Hh*Yy)       /* 768 */
#define ALPHA 0.1f
#define BETA 0.125f
#define LN_EPS 1e-5f
#define SLICE ((size_t)BN_TOT * Dd)      /* 3,145,728 elements per update partial */

// ---------------------------------------------------------------- LayerNorm -> f16 g
__global__ __launch_bounds__(256) void k_ln(const float* __restrict__ x,
                                            const float* __restrict__ gamma,
                                            const float* __restrict__ delta,
                                            f16* __restrict__ g) {
  int row = blockIdx.x;
  const float* xr = x + (size_t)row * Dd;
  f16* gr = g + (size_t)row * Dd;
  int t = threadIdx.x;
  float v0 = xr[t], v1 = xr[t + 256], v2 = xr[t + 512];
  float s = v0 + v1 + v2;
  float ss = v0 * v0 + v1 * v1 + v2 * v2;
#pragma unroll
  for (int o = 32; o; o >>= 1) {
    s += __shfl_xor(s, o);
    ss += __shfl_xor(ss, o);
  }
  __shared__ float red[8];
  int wave = t >> 6;
  if ((t & 63) == 0) { red[wave] = s; red[4 + wave] = ss; }
  __syncthreads();
  float ts = red[0] + red[1] + red[2] + red[3];
  float tss = red[4] + red[5] + red[6] + red[7];
  float mu = ts * (1.0f / Dd);
  float var = tss * (1.0f / Dd) - mu * mu;
  float rstd = rsqrtf(var + LN_EPS);
  gr[t]       = (f16)(gamma[t]       * (v0 - mu) * rstd + delta[t]);
  gr[t + 256] = (f16)(gamma[t + 256] * (v1 - mu) * rstd + delta[t + 256]);
  gr[t + 512] = (f16)(gamma[t + 512] * (v2 - mu) * rstd + delta[t + 512]);
}

// ------------------------- x += sum(6 f16 partials); then LayerNorm -> f16 g
__global__ __launch_bounds__(256) void k_lnred(float* __restrict__ x,
                                               const float* __restrict__ gamma,
                                               const float* __restrict__ delta,
                                               f16* __restrict__ g,
                                               const f16* __restrict__ p03,   // slices 0..3 (SP region)
                                               const f16* __restrict__ p4,
                                               const f16* __restrict__ p5) {
  int row = blockIdx.x;
  float* xr = x + (size_t)row * Dd;
  f16* gr = g + (size_t)row * Dd;
  int t = threadIdx.x;
  float v[3];
#pragma unroll
  for (int e = 0; e < 3; ++e) {
    int c = t + e * 256;
    size_t off = (size_t)row * Dd + c;
    float add = (float)p03[off] + (float)p03[off + SLICE] + (float)p03[off + 2 * SLICE] +
                (float)p03[off + 3 * SLICE] + (float)p4[off] + (float)p5[off];
    v[e] = xr[c] + add;
    xr[c] = v[e];
  }
  float s = v[0] + v[1] + v[2];
  float ss = v[0] * v[0] + v[1] * v[1] + v[2] * v[2];
#pragma unroll
  for (int o = 32; o; o >>= 1) {
    s += __shfl_xor(s, o);
    ss += __shfl_xor(ss, o);
  }
  __shared__ float red[8];
  int wave = t >> 6;
  if ((t & 63) == 0) { red[wave] = s; red[4 + wave] = ss; }
  __syncthreads();
  float ts = red[0] + red[1] + red[2] + red[3];
  float tss = red[4] + red[5] + red[6] + red[7];
  float mu = ts * (1.0f / Dd);
  float var = tss * (1.0f / Dd) - mu * mu;
  float rstd = rsqrtf(var + LN_EPS);
#pragma unroll
  for (int e = 0; e < 3; ++e) {
    int c = t + e * 256;
    gr[c] = (f16)(gamma[c] * (v[e] - mu) * rstd + delta[c]);
  }
}

// ------------------------------------- final x += sum(6 f16 partials) (no LN)
__global__ __launch_bounds__(256) void k_redfin(float* __restrict__ x,
                                                const f16* __restrict__ p03,
                                                const f16* __restrict__ p4,
                                                const f16* __restrict__ p5) {
  int row = blockIdx.x;
  float* xr = x + (size_t)row * Dd;
  int t = threadIdx.x;
#pragma unroll
  for (int e = 0; e < 3; ++e) {
    int c = t + e * 256;
    size_t off = (size_t)row * Dd + c;
    float add = (float)p03[off] + (float)p03[off + SLICE] + (float)p03[off + 2 * SLICE] +
                (float)p03[off + 3 * SLICE] + (float)p4[off] + (float)p5[off];
    xr[c] += add;
  }
}

// ---------------------------------------- fp32 [R][C] -> f16 copy + f16 transpose
__global__ __launch_bounds__(256) void k_cvt_tr(const float* __restrict__ in, int R, int C,
                                                f16* __restrict__ outB, f16* __restrict__ outT) {
  __shared__ float tile[64][65];
  int r0 = blockIdx.y * 64, c0 = blockIdx.x * 64;
  int tid = threadIdx.x;
#pragma unroll
  for (int e = 0; e < 16; ++e) {
    int idx = e * 256 + tid;
    int r = idx >> 6, c = idx & 63;
    float v = in[(size_t)(r0 + r) * C + c0 + c];
    tile[r][c] = v;
    outB[(size_t)(r0 + r) * C + c0 + c] = (f16)v;
  }
  __syncthreads();
#pragma unroll
  for (int e = 0; e < 16; ++e) {
    int idx = e * 256 + tid;
    int rr = idx >> 6, c = idx & 63;
    outT[(size_t)(c0 + rr) * R + r0 + c] = (f16)tile[c][rr];
  }
}

// ------------------------------------------------------------ MFMA GEMM core
__device__ __forceinline__ void gl16(const f16* g, f16* l) {
  __builtin_amdgcn_global_load_lds(
      (const __attribute__((address_space(1))) void*)g,
      (__attribute__((address_space(3))) void*)l, 16, 0, 0);
}

template<int FM, int FN>
__device__ __forceinline__ void zacc(f32x4 (&a)[FM][FN]) {
  f32x4 z = {0.f, 0.f, 0.f, 0.f};
#pragma unroll
  for (int i = 0; i < FM; ++i)
#pragma unroll
    for (int j = 0; j < FN; ++j) a[i][j] = z;
}

template<int BM, int BN, int WM, int WN>
__device__ __forceinline__ void gemm_core(const f16* __restrict__ A, int lda, int row0,
                                          const f16* __restrict__ Bt, int ldb, int col0,
                                          int K,
                                          f32x4 (&acc)[BM / WM / 16][BN / WN / 16],
                                          f16* sA, f16* sB) {
  constexpr int FM = BM / WM / 16, FN = BN / WN / 16;
  const int tid = threadIdx.x;
  const int w = tid >> 6, lane = tid & 63;
  const int wm = (WN == 1) ? w : (w >> 1);
  const int wn = (WN == 1) ? 0 : (w & 1);
  const int m0 = wm * (BM / WM), n0 = wn * (BN / WN);
  const int lr = lane & 15, lk = lane >> 4;
  const int srow = lane >> 2;            // staging: lane -> row-within-16
  const int scol = (lane & 3) * 8;       // staging: lane -> k-chunk (8 halves)
  for (int k0 = 0; k0 < K; k0 += 32) {
#pragma unroll
    for (int t = 0; t < BM / 64; ++t) {  // wave w stages rows [w*BM/4 + t*16, +16)
      int r0 = w * (BM / 4) + t * 16;
      gl16(A + (size_t)(row0 + r0 + srow) * lda + k0 + scol, sA + r0 * 32);
    }
#pragma unroll
    for (int t = 0; t < BN / 64; ++t) {
      int r0 = w * (BN / 4) + t * 16;
      gl16(Bt + (size_t)(col0 + r0 + srow) * ldb + k0 + scol, sB + r0 * 32);
    }
    __syncthreads();                     // compiler drains vmcnt before barrier
    half8 af[FM], bfr[FN];
#pragma unroll
    for (int i = 0; i < FM; ++i)
      af[i] = *(const half8*)(sA + (m0 + i * 16 + lr) * 32 + lk * 8);
#pragma unroll
    for (int j = 0; j < FN; ++j)
      bfr[j] = *(const half8*)(sB + (n0 + j * 16 + lr) * 32 + lk * 8);
#pragma unroll
    for (int i = 0; i < FM; ++i)
#pragma unroll
      for (int j = 0; j < FN; ++j)
        acc[i][j] = __builtin_amdgcn_mfma_f32_16x16x32_f16(af[i], bfr[j], acc[i][j], 0, 0, 0);
    __syncthreads();
  }
}

// ---------------------------------------------------- q/k projection + transposed copies
// grid (6, 32, 2) = 384 blocks, XCD-swizzled (384/8=48, 48%8==0)
__global__ __launch_bounds__(256) void k_qkproj(const f16* __restrict__ g,
                                                const f16* __restrict__ Wqh,
                                                const f16* __restrict__ Wkh,
                                                f16* __restrict__ q, f16* __restrict__ k,
                                                f16* __restrict__ qT, f16* __restrict__ kT) {
  __shared__ f16 sA[128 * 32], sB[128 * 32];
  int lin = blockIdx.x + blockIdx.y * 6 + blockIdx.z * 192;
  int swz = (lin & 7) * 48 + (lin >> 3);
  int col0 = (swz % 6) * 128;
  int row0 = ((swz / 6) & 31) * 128;
  int zq = swz / 192;
  const f16* Wh = zq ? Wkh : Wqh;
  f16* out = zq ? k : q;
  f16* outT = zq ? kT : qT;
  f32x4 acc[4][4];
  zacc(acc);
  gemm_core<128, 128, 2, 2>(g, Dd, row0, Wh, Dd, col0, Dd, acc, sA, sB);
  int w = threadIdx.x >> 6, lane = threadIdx.x & 63;
  int m0 = (w >> 1) * 64, n0 = (w & 1) * 64, lr = lane & 15, lk = lane >> 4;
#pragma unroll
  for (int i = 0; i < 4; ++i)
#pragma unroll
    for (int j = 0; j < 4; ++j) {
      int r0g = row0 + m0 + i * 16 + lk * 4;
      int cg = col0 + n0 + j * 16 + lr;
      half4 hv;
#pragma unroll
      for (int p = 0; p < 4; ++p) {
        f16 h1 = (f16)acc[i][j][p];
        out[(size_t)(r0g + p) * HY + cg] = h1;
        hv[p] = h1;
      }
      int b = r0g >> 9, nl = r0g & 511;
      int h = cg >> 6, y = cg & 63;
      *(half4*)(outT + (((size_t)b * Hh + h) * Yy + y) * Nn + nl) = hv;
    }
}

// -------------------------------------------------------- scores S = beta * q k^T
__global__ __launch_bounds__(256) void k_scores(const f16* __restrict__ q,
                                                const f16* __restrict__ k,
                                                f16* __restrict__ SP, int zbase) {
  __shared__ f16 sA[128 * 32], sB[128 * 32];
  int zg = zbase + blockIdx.z;
  int b = zg / Hh, h = zg - b * Hh;
  const f16* A = q + (size_t)b * Nn * HY + h * Yy;
  const f16* Bt = k + (size_t)b * Nn * HY + h * Yy;
  int row0 = blockIdx.y * 128, col0 = blockIdx.x * 128;
  f32x4 acc[4][4];
  zacc(acc);
  gemm_core<128, 128, 2, 2>(A, HY, row0, Bt, HY, col0, Yy, acc, sA, sB);
  f16* S = SP + (size_t)blockIdx.z * Nn * Nn;
  int w = threadIdx.x >> 6, lane = threadIdx.x & 63;
  int m0 = (w >> 1) * 64, n0 = (w & 1) * 64, lr = lane & 15, lk = lane >> 4;
#pragma unroll
  for (int i = 0; i < 4; ++i)
#pragma unroll
    for (int j = 0; j < 4; ++j) {
      int r0g = row0 + m0 + i * 16 + lk * 4;
      int cg = col0 + n0 + j * 16 + lr;
#pragma unroll
      for (int p = 0; p < 4; ++p)
        S[(size_t)(r0g + p) * Nn + cg] = (f16)(BETA * acc[i][j][p]);
    }
}

// ------------------------------------------------------------- row softmax (in-place f16)
__global__ __launch_bounds__(256) void k_softmax(f16* __restrict__ SP) {
  f16* row = SP + ((size_t)blockIdx.y * Nn + blockIdx.x) * Nn;
  int t = threadIdx.x;
  float a = (float)row[t], b = (float)row[t + 256];
  float mx = fmaxf(a, b);
#pragma unroll
  for (int o = 32; o; o >>= 1) mx = fmaxf(mx, __shfl_xor(mx, o));
  __shared__ float rm[4], rs[4];
  int wave = t >> 6;
  if ((t & 63) == 0) rm[wave] = mx;
  __syncthreads();
  mx = fmaxf(fmaxf(rm[0], rm[1]), fmaxf(rm[2], rm[3]));
  float ea = __expf(a - mx), eb = __expf(b - mx);
  float s = ea + eb;
#pragma unroll
  for (int o = 32; o; o >>= 1) s += __shfl_xor(s, o);
  if ((t & 63) == 0) rs[wave] = s;
  __syncthreads();
  float inv = 1.0f / (rs[0] + rs[1] + rs[2] + rs[3]);
  row[t] = (f16)(ea * inv);
  row[t + 256] = (f16)(eb * inv);
}

// ------------------------------------------------------------- P -> P^T (per z)
__global__ __launch_bounds__(256) void k_transP(const f16* __restrict__ SP, f16* __restrict__ PT) {
  __shared__ f16 tile[64][72];
  const f16* P = SP + (size_t)blockIdx.z * Nn * Nn;
  f16* T = PT + (size_t)blockIdx.z * Nn * Nn;
  int nb = blockIdx.y * 64, mb = blockIdx.x * 64;
  int tid = threadIdx.x;
#pragma unroll
  for (int e = 0; e < 2; ++e) {
    int ci = e * 256 + tid;
    int r = ci >> 3, c = (ci & 7) * 8;
    half8 v = *(const half8*)(P + (size_t)(nb + r) * Nn + mb + c);
#pragma unroll
    for (int qq = 0; qq < 8; ++qq) tile[r][c + qq] = v[qq];
  }
  __syncthreads();
#pragma unroll
  for (int e = 0; e < 2; ++e) {
    int ci = e * 256 + tid;
    int r = ci >> 3, c = (ci & 7) * 8;
    half8 v;
#pragma unroll
    for (int qq = 0; qq < 8; ++qq) v[qq] = tile[c + qq][r];
    *(half8*)(T + (size_t)(mb + r) * Nn + nb + c) = v;
  }
}

// --------------------------------------------- dq = P*K and dk = P^T*Q, one launch
__global__ __launch_bounds__(256) void k_dqdk(const f16* __restrict__ SP,
                                              const f16* __restrict__ PT,
                                              const f16* __restrict__ qT,
                                              const f16* __restrict__ kT,
                                              f16* __restrict__ dq,
                                              f16* __restrict__ dk, int zbase) {
  __shared__ f16 sA[128 * 32], sB[64 * 32];
  int which = blockIdx.z & 1, zloc = blockIdx.z >> 1;
  int zg = zbase + zloc;
  int b = zg / Hh, h = zg - b * Hh;
  const f16* A = (which ? PT : SP) + (size_t)zloc * Nn * Nn;
  const f16* Bt = (which ? qT : kT) + (size_t)zg * Yy * Nn;
  f16* out = which ? dk : dq;
  int row0 = blockIdx.y * 128;
  f32x4 acc[2][4];
  zacc(acc);
  gemm_core<128, 64, 4, 1>(A, Nn, row0, Bt, Nn, 0, Nn, acc, sA, sB);
  int w = threadIdx.x >> 6, lane = threadIdx.x & 63;
  int m0 = w * 32, lr = lane & 15, lk = lane >> 4;
#pragma unroll
  for (int i = 0; i < 2; ++i)
#pragma unroll
    for (int j = 0; j < 4; ++j) {
      int r0g = row0 + m0 + i * 16 + lk * 4;
      int cg = j * 16 + lr;
#pragma unroll
      for (int p = 0; p < 4; ++p)
        out[(size_t)(b * Nn + r0g + p) * HY + h * Yy + cg] = (f16)acc[i][j][p];
    }
}

// ----------------- update partials: alpha*(dq Wq | dk Wk | hid xi), 6 K=768 slices
// grid (6, 32, 6) = 1152 blocks, XCD-swizzled. Slices stream f16 into dead ws:
// z'=0..3 -> SP region quarters; z'=4 -> q; z'=5 -> k (all dead at this point).
__global__ __launch_bounds__(256) void k_update(const f16* __restrict__ dq,
                                                const f16* __restrict__ dk,
                                                const f16* __restrict__ WqT,
                                                const f16* __restrict__ WkT,
                                                const f16* __restrict__ hid,
                                                const f16* __restrict__ xiT,
                                                f16* __restrict__ p03,
                                                f16* __restrict__ p4,
                                                f16* __restrict__ p5) {
  __shared__ f16 sA[128 * 32], sB[128 * 32];
  int lin = blockIdx.x + blockIdx.y * 6 + blockIdx.z * 192;
  int swz = (lin & 7) * 144 + (lin >> 3);
  int col0 = (swz % 6) * 128;
  int row0 = ((swz / 6) & 31) * 128;
  int zz = swz / 192;
  const f16* A; const f16* Bt; int lda, ldb;
  if (zz == 0)      { A = dq; Bt = WqT; lda = HY; ldb = HY; }
  else if (zz == 1) { A = dk; Bt = WkT; lda = HY; ldb = HY; }
  else              { A = hid + (zz - 2) * 768; Bt = xiT + (zz - 2) * 768; lda = Mm; ldb = Mm; }
  // partial slice destination: zz=0,1 -> p4,p5; zz=2..5 -> p03 quarters
  f16* outp = (zz == 0) ? p4 : (zz == 1) ? p5 : p03 + (size_t)(zz - 2) * SLICE;
  f32x4 acc[4][4];
  zacc(acc);
  gemm_core<128, 128, 2, 2>(A, lda, row0, Bt, ldb, col0, 768, acc, sA, sB);
  int w = threadIdx.x >> 6, lane = threadIdx.x & 63;
  int m0 = (w >> 1) * 64, n0 = (w & 1) * 64, lr = lane & 15, lk = lane >> 4;
#pragma unroll
  for (int i = 0; i < 4; ++i)
#pragma unroll
    for (int j = 0; j < 4; ++j) {
      int r0g = row0 + m0 + i * 16 + lk * 4;
      int cg = col0 + n0 + j * 16 + lr;
#pragma unroll
      for (int p = 0; p < 4; ++p)
        outp[(size_t)(r0g + p) * Dd + cg] = (f16)(ALPHA * acc[i][j][p]);
    }
}

// ----------------------------------------------- hid = relu(g xi^T)
// grid (24, 32) = 768 blocks, XCD-swizzled (768/8=96, 96%8==0)
__global__ __launch_bounds__(256) void k_hid(const f16* __restrict__ g, const f16* __restrict__ xih,
                                             f16* __restrict__ hid) {
  __shared__ f16 sA[128 * 32], sB[128 * 32];
  int lin = blockIdx.x + blockIdx.y * 24;
  int swz = (lin & 7) * 96 + (lin >> 3);
  int col0 = (swz % 24) * 128;
  int row0 = (swz / 24) * 128;
  f32x4 acc[4][4];
  zacc(acc);
  gemm_core<128, 128, 2, 2>(g, Dd, row0, xih, Dd, col0, Dd, acc, sA, sB);
  int w = threadIdx.x >> 6, lane = threadIdx.x & 63;
  int m0 = (w >> 1) * 64, n0 = (w & 1) * 64, lr = lane & 15, lk = lane >> 4;
#pragma unroll
  for (int i = 0; i < 4; ++i)
#pragma unroll
    for (int j = 0; j < 4; ++j) {
      int r0g = row0 + m0 + i * 16 + lk * 4;
      int cg = col0 + n0 + j * 16 + lr;
#pragma unroll
      for (int p = 0; p < 4; ++p)
        hid[(size_t)(r0g + p) * Mm + cg] = (f16)fmaxf(acc[i][j][p], 0.0f);
    }
}

// --------------------------------------------------------------------------
extern "C" void kernel_launch(void* const* d_in, const int* in_sizes, int n_in,
                              void* d_out, int out_size, void* d_ws, size_t ws_size,
                              hipStream_t stream) {
  const float* x_in  = (const float*)d_in[0];
  const float* Wq    = (const float*)d_in[1];
  const float* Wk    = (const float*)d_in[2];
  const float* xi    = (const float*)d_in[3];
  const float* gamma = (const float*)d_in[4];
  const float* delta = (const float*)d_in[5];
  float* x = (float*)d_out;

  // ---- workspace carve (f16 buffers, 256B aligned)
  char* p = (char*)d_ws;
  size_t used = 0;
  auto alloc = [&](size_t elems) -> f16* {
    size_t bytes = (elems * sizeof(f16) + 255) & ~(size_t)255;
    f16* r = (f16*)(p + used);
    used += bytes;
    return r;
  };
  const size_t SZ = (size_t)BN_TOT * HY;       // 3,145,728
  f16* g   = alloc(SZ);
  f16* q   = alloc(SZ);                        // aliased: update partial slice 4
  f16* k   = alloc(SZ);                        // aliased: update partial slice 5
  f16* qT  = alloc(SZ);
  f16* kT  = alloc(SZ);
  f16* dq  = alloc(SZ);
  f16* dk  = alloc(SZ);
  f16* Wqh = alloc((size_t)HY * Dd);
  f16* Wkh = alloc((size_t)HY * Dd);
  f16* WqT = alloc((size_t)Dd * HY);
  f16* WkT = alloc((size_t)Dd * HY);
  f16* xih = alloc((size_t)Mm * Dd);
  f16* xiT = alloc((size_t)Dd * Mm);
  f16* SP  = alloc((size_t)48 * Nn * Nn);      // scores/P; aliased: partial slices 0..3
  f16* PTH = alloc((size_t)48 * Nn * Nn);      // P^T, later reused as hid [4096][3072]
  f16* hid = PTH;                              // same element count: 48*512*512 == 4096*3072
  if (used > ws_size) return;

  hipMemcpyAsync(x, x_in, SZ * sizeof(float), hipMemcpyDeviceToDevice, stream);

  // one-time weight conversion + transposes
  k_cvt_tr<<<dim3(Dd / 64, HY / 64), 256, 0, stream>>>(Wq, HY, Dd, Wqh, WqT);
  k_cvt_tr<<<dim3(Dd / 64, HY / 64), 256, 0, stream>>>(Wk, HY, Dd, Wkh, WkT);
  k_cvt_tr<<<dim3(Dd / 64, Mm / 64), 256, 0, stream>>>(xi, Mm, Dd, xih, xiT);

  for (int step = 0; step < 12; ++step) {
    if (step == 0)
      k_ln<<<BN_TOT, 256, 0, stream>>>(x, gamma, delta, g);
    else
      k_lnred<<<BN_TOT, 256, 0, stream>>>(x, gamma, delta, g, SP, q, k);
    k_qkproj<<<dim3(6, 32, 2), 256, 0, stream>>>(g, Wqh, Wkh, q, k, qT, kT);
    for (int half = 0; half < 2; ++half) {
      int zbase = half * 48;
      k_scores<<<dim3(Nn / 128, Nn / 128, 48), 256, 0, stream>>>(q, k, SP, zbase);
      k_softmax<<<dim3(Nn, 48), 256, 0, stream>>>(SP);
      k_transP<<<dim3(8, 8, 48), 256, 0, stream>>>(SP, PTH);
      k_dqdk<<<dim3(1, Nn / 128, 96), 256, 0, stream>>>(SP, PTH, qT, kT, dq, dk, zbase);
    }
    k_hid<<<dim3(24, 32), 256, 0, stream>>>(g, xih, hid);
    k_update<<<dim3(6, 32, 6), 256, 0, stream>>>(dq, dk, WqT, WkT, hid, xiT, SP, q, k);
  }
  k_redfin<<<BN_TOT, 256, 0, stream>>>(x, SP, q, k);
}

// Round 10
// 2244.605 us; speedup vs baseline: 10.6936x; 1.1899x over previous
//
#include <hip/hip_runtime.h>

typedef _Float16 f16;
typedef __attribute__((ext_vector_type(8))) _Float16 half8;
typedef __attribute__((ext_vector_type(4))) _Float16 half4;
typedef __attribute__((ext_vector_type(4))) float f32x4;

#define Bb 8
#define Nn 512
#define Dd 768
#define Hh 12
#define Yy 64
#define Mm 3072
#define BN_TOT (Bb*Nn)   /* 4096 */
#define HY (Hh*Yy)       /* 768 */
#define ALPHA 0.1f
#define BETA 0.125f
#define LN_EPS 1e-5f
#define SLICE ((size_t)BN_TOT * Dd)      /* 3,145,728 elements per update partial */

// ---------------------------------------------------------------- LayerNorm -> f16 g
__global__ __launch_bounds__(256) void k_ln(const float* __restrict__ x,
                                            const float* __restrict__ gamma,
                                            const float* __restrict__ delta,
                                            f16* __restrict__ g) {
  int row = blockIdx.x;
  const float* xr = x + (size_t)row * Dd;
  f16* gr = g + (size_t)row * Dd;
  int t = threadIdx.x;
  float v0 = xr[t], v1 = xr[t + 256], v2 = xr[t + 512];
  float s = v0 + v1 + v2;
  float ss = v0 * v0 + v1 * v1 + v2 * v2;
#pragma unroll
  for (int o = 32; o; o >>= 1) {
    s += __shfl_xor(s, o);
    ss += __shfl_xor(ss, o);
  }
  __shared__ float red[8];
  int wave = t >> 6;
  if ((t & 63) == 0) { red[wave] = s; red[4 + wave] = ss; }
  __syncthreads();
  float ts = red[0] + red[1] + red[2] + red[3];
  float tss = red[4] + red[5] + red[6] + red[7];
  float mu = ts * (1.0f / Dd);
  float var = tss * (1.0f / Dd) - mu * mu;
  float rstd = rsqrtf(var + LN_EPS);
  gr[t]       = (f16)(gamma[t]       * (v0 - mu) * rstd + delta[t]);
  gr[t + 256] = (f16)(gamma[t + 256] * (v1 - mu) * rstd + delta[t + 256]);
  gr[t + 512] = (f16)(gamma[t + 512] * (v2 - mu) * rstd + delta[t + 512]);
}

// ------------------------- x += sum(6 f16 partials); then LayerNorm -> f16 g
__global__ __launch_bounds__(256) void k_lnred(float* __restrict__ x,
                                               const float* __restrict__ gamma,
                                               const float* __restrict__ delta,
                                               f16* __restrict__ g,
                                               const f16* __restrict__ p03,   // slices 0..3 (SP region)
                                               const f16* __restrict__ p4,
                                               const f16* __restrict__ p5) {
  int row = blockIdx.x;
  float* xr = x + (size_t)row * Dd;
  f16* gr = g + (size_t)row * Dd;
  int t = threadIdx.x;
  float v[3];
#pragma unroll
  for (int e = 0; e < 3; ++e) {
    int c = t + e * 256;
    size_t off = (size_t)row * Dd + c;
    float add = (float)p03[off] + (float)p03[off + SLICE] + (float)p03[off + 2 * SLICE] +
                (float)p03[off + 3 * SLICE] + (float)p4[off] + (float)p5[off];
    v[e] = xr[c] + add;
    xr[c] = v[e];
  }
  float s = v[0] + v[1] + v[2];
  float ss = v[0] * v[0] + v[1] * v[1] + v[2] * v[2];
#pragma unroll
  for (int o = 32; o; o >>= 1) {
    s += __shfl_xor(s, o);
    ss += __shfl_xor(ss, o);
  }
  __shared__ float red[8];
  int wave = t >> 6;
  if ((t & 63) == 0) { red[wave] = s; red[4 + wave] = ss; }
  __syncthreads();
  float ts = red[0] + red[1] + red[2] + red[3];
  float tss = red[4] + red[5] + red[6] + red[7];
  float mu = ts * (1.0f / Dd);
  float var = tss * (1.0f / Dd) - mu * mu;
  float rstd = rsqrtf(var + LN_EPS);
#pragma unroll
  for (int e = 0; e < 3; ++e) {
    int c = t + e * 256;
    gr[c] = (f16)(gamma[c] * (v[e] - mu) * rstd + delta[c]);
  }
}

// ------------------------------------- final x += sum(6 f16 partials) (no LN)
__global__ __launch_bounds__(256) void k_redfin(float* __restrict__ x,
                                                const f16* __restrict__ p03,
                                                const f16* __restrict__ p4,
                                                const f16* __restrict__ p5) {
  int row = blockIdx.x;
  float* xr = x + (size_t)row * Dd;
  int t = threadIdx.x;
#pragma unroll
  for (int e = 0; e < 3; ++e) {
    int c = t + e * 256;
    size_t off = (size_t)row * Dd + c;
    float add = (float)p03[off] + (float)p03[off + SLICE] + (float)p03[off + 2 * SLICE] +
                (float)p03[off + 3 * SLICE] + (float)p4[off] + (float)p5[off];
    xr[c] += add;
  }
}

// ---------------------------------------- fp32 [R][C] -> f16 copy + f16 transpose
__global__ __launch_bounds__(256) void k_cvt_tr(const float* __restrict__ in, int R, int C,
                                                f16* __restrict__ outB, f16* __restrict__ outT) {
  __shared__ float tile[64][65];
  int r0 = blockIdx.y * 64, c0 = blockIdx.x * 64;
  int tid = threadIdx.x;
#pragma unroll
  for (int e = 0; e < 16; ++e) {
    int idx = e * 256 + tid;
    int r = idx >> 6, c = idx & 63;
    float v = in[(size_t)(r0 + r) * C + c0 + c];
    tile[r][c] = v;
    outB[(size_t)(r0 + r) * C + c0 + c] = (f16)v;
  }
  __syncthreads();
#pragma unroll
  for (int e = 0; e < 16; ++e) {
    int idx = e * 256 + tid;
    int rr = idx >> 6, c = idx & 63;
    outT[(size_t)(c0 + rr) * R + r0 + c] = (f16)tile[c][rr];
  }
}

// ------------------------------------------------------------ MFMA GEMM core
__device__ __forceinline__ void gl16(const f16* g, f16* l) {
  __builtin_amdgcn_global_load_lds(
      (const __attribute__((address_space(1))) void*)g,
      (__attribute__((address_space(3))) void*)l, 16, 0, 0);
}

template<int FM, int FN>
__device__ __forceinline__ void zacc(f32x4 (&a)[FM][FN]) {
  f32x4 z = {0.f, 0.f, 0.f, 0.f};
#pragma unroll
  for (int i = 0; i < FM; ++i)
#pragma unroll
    for (int j = 0; j < FN; ++j) a[i][j] = z;
}

template<int BM, int BN, int WM, int WN>
__device__ __forceinline__ void gemm_core(const f16* __restrict__ A, int lda, int row0,
                                          const f16* __restrict__ Bt, int ldb, int col0,
                                          int K,
                                          f32x4 (&acc)[BM / WM / 16][BN / WN / 16],
                                          f16* sA, f16* sB) {
  constexpr int FM = BM / WM / 16, FN = BN / WN / 16;
  const int tid = threadIdx.x;
  const int w = tid >> 6, lane = tid & 63;
  const int wm = (WN == 1) ? w : (w >> 1);
  const int wn = (WN == 1) ? 0 : (w & 1);
  const int m0 = wm * (BM / WM), n0 = wn * (BN / WN);
  const int lr = lane & 15, lk = lane >> 4;
  const int srow = lane >> 2;            // staging: lane -> row-within-16
  const int scol = (lane & 3) * 8;       // staging: lane -> k-chunk (8 halves)
  for (int k0 = 0; k0 < K; k0 += 32) {
#pragma unroll
    for (int t = 0; t < BM / 64; ++t) {  // wave w stages rows [w*BM/4 + t*16, +16)
      int r0 = w * (BM / 4) + t * 16;
      gl16(A + (size_t)(row0 + r0 + srow) * lda + k0 + scol, sA + r0 * 32);
    }
#pragma unroll
    for (int t = 0; t < BN / 64; ++t) {
      int r0 = w * (BN / 4) + t * 16;
      gl16(Bt + (size_t)(col0 + r0 + srow) * ldb + k0 + scol, sB + r0 * 32);
    }
    __syncthreads();                     // compiler drains vmcnt before barrier
    half8 af[FM], bfr[FN];
#pragma unroll
    for (int i = 0; i < FM; ++i)
      af[i] = *(const half8*)(sA + (m0 + i * 16 + lr) * 32 + lk * 8);
#pragma unroll
    for (int j = 0; j < FN; ++j)
      bfr[j] = *(const half8*)(sB + (n0 + j * 16 + lr) * 32 + lk * 8);
#pragma unroll
    for (int i = 0; i < FM; ++i)
#pragma unroll
      for (int j = 0; j < FN; ++j)
        acc[i][j] = __builtin_amdgcn_mfma_f32_16x16x32_f16(af[i], bfr[j], acc[i][j], 0, 0, 0);
    __syncthreads();
  }
}

// ---------------------------------------------------- q/k projection + transposed copies
// grid (6, 32, 2) = 384 blocks, XCD-swizzled (384/8=48, 48%8==0)
__global__ __launch_bounds__(256) void k_qkproj(const f16* __restrict__ g,
                                                const f16* __restrict__ Wqh,
                                                const f16* __restrict__ Wkh,
                                                f16* __restrict__ q, f16* __restrict__ k,
                                                f16* __restrict__ qT, f16* __restrict__ kT) {
  __shared__ f16 sA[128 * 32], sB[128 * 32];
  int lin = blockIdx.x + blockIdx.y * 6 + blockIdx.z * 192;
  int swz = (lin & 7) * 48 + (lin >> 3);
  int col0 = (swz % 6) * 128;
  int row0 = ((swz / 6) & 31) * 128;
  int zq = swz / 192;
  const f16* Wh = zq ? Wkh : Wqh;
  f16* out = zq ? k : q;
  f16* outT = zq ? kT : qT;
  f32x4 acc[4][4];
  zacc(acc);
  gemm_core<128, 128, 2, 2>(g, Dd, row0, Wh, Dd, col0, Dd, acc, sA, sB);
  int w = threadIdx.x >> 6, lane = threadIdx.x & 63;
  int m0 = (w >> 1) * 64, n0 = (w & 1) * 64, lr = lane & 15, lk = lane >> 4;
#pragma unroll
  for (int i = 0; i < 4; ++i)
#pragma unroll
    for (int j = 0; j < 4; ++j) {
      int r0g = row0 + m0 + i * 16 + lk * 4;
      int cg = col0 + n0 + j * 16 + lr;
      half4 hv;
#pragma unroll
      for (int p = 0; p < 4; ++p) {
        f16 h1 = (f16)acc[i][j][p];
        out[(size_t)(r0g + p) * HY + cg] = h1;
        hv[p] = h1;
      }
      int b = r0g >> 9, nl = r0g & 511;
      int h = cg >> 6, y = cg & 63;
      *(half4*)(outT + (((size_t)b * Hh + h) * Yy + y) * Nn + nl) = hv;
    }
}

// ---------------- fused scores + softmax + dual-layout write (P and P^T)
// Each block: one head z, 32 rows x all 512 cols. 4 waves x 128 cols.
// grid (16, 48)
__global__ __launch_bounds__(256) void k_attn(const f16* __restrict__ q,
                                              const f16* __restrict__ k,
                                              f16* __restrict__ SP,
                                              f16* __restrict__ PT, int zbase) {
  __shared__ f16 sA[32 * 32], sB[512 * 32];
  __shared__ float redm[4][32], redl[4][32];
  int zloc = blockIdx.y;
  int zg = zbase + zloc;
  int b = zg / Hh, h = zg - b * Hh;
  const f16* A = q + (size_t)b * Nn * HY + h * Yy;   // [512][64], lda=HY
  const f16* Bt = k + (size_t)b * Nn * HY + h * Yy;
  int r0 = blockIdx.x * 32;
  int tid = threadIdx.x, w = tid >> 6, lane = tid & 63;
  int lr = lane & 15, lk = lane >> 4;
  int srow = lane >> 2, scol = (lane & 3) * 8;
  f32x4 acc[2][8];
  zacc(acc);
  for (int k0 = 0; k0 < Yy; k0 += 32) {
    if (w < 2)
      gl16(A + (size_t)(r0 + w * 16 + srow) * HY + k0 + scol, sA + (w * 16) * 32);
#pragma unroll
    for (int t = 0; t < 8; ++t)
      gl16(Bt + (size_t)(w * 128 + t * 16 + srow) * HY + k0 + scol, sB + (w * 128 + t * 16) * 32);
    __syncthreads();
    half8 af[2], bfr[8];
#pragma unroll
    for (int i = 0; i < 2; ++i)
      af[i] = *(const half8*)(sA + (i * 16 + lr) * 32 + lk * 8);
#pragma unroll
    for (int j = 0; j < 8; ++j)
      bfr[j] = *(const half8*)(sB + (w * 128 + j * 16 + lr) * 32 + lk * 8);
#pragma unroll
    for (int i = 0; i < 2; ++i)
#pragma unroll
      for (int j = 0; j < 8; ++j)
        acc[i][j] = __builtin_amdgcn_mfma_f32_16x16x32_f16(af[i], bfr[j], acc[i][j], 0, 0, 0);
    __syncthreads();
  }
  // scale by beta, per-row max (rows: i*16 + lk*4 + p; cols per lane: j*16+lr)
  float pm[2][4];
#pragma unroll
  for (int i = 0; i < 2; ++i)
#pragma unroll
    for (int p = 0; p < 4; ++p) {
      float m = -1e30f;
#pragma unroll
      for (int j = 0; j < 8; ++j) {
        acc[i][j][p] *= BETA;
        m = fmaxf(m, acc[i][j][p]);
      }
      pm[i][p] = m;
    }
#pragma unroll
  for (int o = 1; o < 16; o <<= 1)
#pragma unroll
    for (int i = 0; i < 2; ++i)
#pragma unroll
      for (int p = 0; p < 4; ++p) pm[i][p] = fmaxf(pm[i][p], __shfl_xor(pm[i][p], o));
  if (lr == 0)
#pragma unroll
    for (int i = 0; i < 2; ++i)
#pragma unroll
      for (int p = 0; p < 4; ++p) redm[w][i * 16 + lk * 4 + p] = pm[i][p];
  __syncthreads();
  float fm[2][4], ps[2][4];
#pragma unroll
  for (int i = 0; i < 2; ++i)
#pragma unroll
    for (int p = 0; p < 4; ++p) {
      int r = i * 16 + lk * 4 + p;
      fm[i][p] = fmaxf(fmaxf(redm[0][r], redm[1][r]), fmaxf(redm[2][r], redm[3][r]));
      ps[i][p] = 0.f;
    }
#pragma unroll
  for (int i = 0; i < 2; ++i)
#pragma unroll
    for (int j = 0; j < 8; ++j)
#pragma unroll
      for (int p = 0; p < 4; ++p) {
        float e = __expf(acc[i][j][p] - fm[i][p]);
        acc[i][j][p] = e;
        ps[i][p] += e;
      }
#pragma unroll
  for (int o = 1; o < 16; o <<= 1)
#pragma unroll
    for (int i = 0; i < 2; ++i)
#pragma unroll
      for (int p = 0; p < 4; ++p) ps[i][p] += __shfl_xor(ps[i][p], o);
  if (lr == 0)
#pragma unroll
    for (int i = 0; i < 2; ++i)
#pragma unroll
      for (int p = 0; p < 4; ++p) redl[w][i * 16 + lk * 4 + p] = ps[i][p];
  __syncthreads();
  float inv[2][4];
#pragma unroll
  for (int i = 0; i < 2; ++i)
#pragma unroll
    for (int p = 0; p < 4; ++p) {
      int r = i * 16 + lk * 4 + p;
      inv[i][p] = 1.0f / (redl[0][r] + redl[1][r] + redl[2][r] + redl[3][r]);
    }
  f16* S = SP + (size_t)zloc * Nn * Nn;
  f16* T = PT + (size_t)zloc * Nn * Nn;
#pragma unroll
  for (int i = 0; i < 2; ++i)
#pragma unroll
    for (int j = 0; j < 8; ++j) {
      int row = r0 + i * 16 + lk * 4;
      int col = w * 128 + j * 16 + lr;
      half4 hv;
#pragma unroll
      for (int p = 0; p < 4; ++p) {
        f16 v = (f16)(acc[i][j][p] * inv[i][p]);
        S[(size_t)(row + p) * Nn + col] = v;
        hv[p] = v;
      }
      *(half4*)(T + (size_t)col * Nn + row) = hv;
    }
}

// --------------------------------------------- dq = P*K and dk = P^T*Q, one launch
__global__ __launch_bounds__(256) void k_dqdk(const f16* __restrict__ SP,
                                              const f16* __restrict__ PT,
                                              const f16* __restrict__ qT,
                                              const f16* __restrict__ kT,
                                              f16* __restrict__ dq,
                                              f16* __restrict__ dk, int zbase) {
  __shared__ f16 sA[128 * 32], sB[64 * 32];
  int which = blockIdx.z & 1, zloc = blockIdx.z >> 1;
  int zg = zbase + zloc;
  int b = zg / Hh, h = zg - b * Hh;
  const f16* A = (which ? PT : SP) + (size_t)zloc * Nn * Nn;
  const f16* Bt = (which ? qT : kT) + (size_t)zg * Yy * Nn;
  f16* out = which ? dk : dq;
  int row0 = blockIdx.y * 128;
  f32x4 acc[2][4];
  zacc(acc);
  gemm_core<128, 64, 4, 1>(A, Nn, row0, Bt, Nn, 0, Nn, acc, sA, sB);
  int w = threadIdx.x >> 6, lane = threadIdx.x & 63;
  int m0 = w * 32, lr = lane & 15, lk = lane >> 4;
#pragma unroll
  for (int i = 0; i < 2; ++i)
#pragma unroll
    for (int j = 0; j < 4; ++j) {
      int r0g = row0 + m0 + i * 16 + lk * 4;
      int cg = j * 16 + lr;
#pragma unroll
      for (int p = 0; p < 4; ++p)
        out[(size_t)(b * Nn + r0g + p) * HY + h * Yy + cg] = (f16)acc[i][j][p];
    }
}

// ----------------- update partials: alpha*(dq Wq | dk Wk | hid xi), 6 K=768 slices
// grid (6, 32, 6) = 1152 blocks, XCD-swizzled. Slices stream f16 into dead ws:
// z'=0..3 -> SP region quarters; z'=4 -> q; z'=5 -> k (all dead at this point).
__global__ __launch_bounds__(256) void k_update(const f16* __restrict__ dq,
                                                const f16* __restrict__ dk,
                                                const f16* __restrict__ WqT,
                                                const f16* __restrict__ WkT,
                                                const f16* __restrict__ hid,
                                                const f16* __restrict__ xiT,
                                                f16* __restrict__ p03,
                                                f16* __restrict__ p4,
                                                f16* __restrict__ p5) {
  __shared__ f16 sA[128 * 32], sB[128 * 32];
  int lin = blockIdx.x + blockIdx.y * 6 + blockIdx.z * 192;
  int swz = (lin & 7) * 144 + (lin >> 3);
  int col0 = (swz % 6) * 128;
  int row0 = ((swz / 6) & 31) * 128;
  int zz = swz / 192;
  const f16* A; const f16* Bt; int lda, ldb;
  if (zz == 0)      { A = dq; Bt = WqT; lda = HY; ldb = HY; }
  else if (zz == 1) { A = dk; Bt = WkT; lda = HY; ldb = HY; }
  else              { A = hid + (zz - 2) * 768; Bt = xiT + (zz - 2) * 768; lda = Mm; ldb = Mm; }
  f16* outp = (zz == 0) ? p4 : (zz == 1) ? p5 : p03 + (size_t)(zz - 2) * SLICE;
  f32x4 acc[4][4];
  zacc(acc);
  gemm_core<128, 128, 2, 2>(A, lda, row0, Bt, ldb, col0, 768, acc, sA, sB);
  int w = threadIdx.x >> 6, lane = threadIdx.x & 63;
  int m0 = (w >> 1) * 64, n0 = (w & 1) * 64, lr = lane & 15, lk = lane >> 4;
#pragma unroll
  for (int i = 0; i < 4; ++i)
#pragma unroll
    for (int j = 0; j < 4; ++j) {
      int r0g = row0 + m0 + i * 16 + lk * 4;
      int cg = col0 + n0 + j * 16 + lr;
#pragma unroll
      for (int p = 0; p < 4; ++p)
        outp[(size_t)(r0g + p) * Dd + cg] = (f16)(ALPHA * acc[i][j][p]);
    }
}

// ----------------------------------------------- hid = relu(g xi^T)
// grid (24, 32) = 768 blocks, XCD-swizzled (768/8=96, 96%8==0)
__global__ __launch_bounds__(256) void k_hid(const f16* __restrict__ g, const f16* __restrict__ xih,
                                             f16* __restrict__ hid) {
  __shared__ f16 sA[128 * 32], sB[128 * 32];
  int lin = blockIdx.x + blockIdx.y * 24;
  int swz = (lin & 7) * 96 + (lin >> 3);
  int col0 = (swz % 24) * 128;
  int row0 = (swz / 24) * 128;
  f32x4 acc[4][4];
  zacc(acc);
  gemm_core<128, 128, 2, 2>(g, Dd, row0, xih, Dd, col0, Dd, acc, sA, sB);
  int w = threadIdx.x >> 6, lane = threadIdx.x & 63;
  int m0 = (w >> 1) * 64, n0 = (w & 1) * 64, lr = lane & 15, lk = lane >> 4;
#pragma unroll
  for (int i = 0; i < 4; ++i)
#pragma unroll
    for (int j = 0; j < 4; ++j) {
      int r0g = row0 + m0 + i * 16 + lk * 4;
      int cg = col0 + n0 + j * 16 + lr;
#pragma unroll
      for (int p = 0; p < 4; ++p)
        hid[(size_t)(r0g + p) * Mm + cg] = (f16)fmaxf(acc[i][j][p], 0.0f);
    }
}

// --------------------------------------------------------------------------
extern "C" void kernel_launch(void* const* d_in, const int* in_sizes, int n_in,
                              void* d_out, int out_size, void* d_ws, size_t ws_size,
                              hipStream_t stream) {
  const float* x_in  = (const float*)d_in[0];
  const float* Wq    = (const float*)d_in[1];
  const float* Wk    = (const float*)d_in[2];
  const float* xi    = (const float*)d_in[3];
  const float* gamma = (const float*)d_in[4];
  const float* delta = (const float*)d_in[5];
  float* x = (float*)d_out;

  // ---- workspace carve (f16 buffers, 256B aligned)
  char* p = (char*)d_ws;
  size_t used = 0;
  auto alloc = [&](size_t elems) -> f16* {
    size_t bytes = (elems * sizeof(f16) + 255) & ~(size_t)255;
    f16* r = (f16*)(p + used);
    used += bytes;
    return r;
  };
  const size_t SZ = (size_t)BN_TOT * HY;       // 3,145,728
  f16* g   = alloc(SZ);
  f16* q   = alloc(SZ);                        // aliased: update partial slice 4
  f16* k   = alloc(SZ);                        // aliased: update partial slice 5
  f16* qT  = alloc(SZ);
  f16* kT  = alloc(SZ);
  f16* dq  = alloc(SZ);
  f16* dk  = alloc(SZ);
  f16* Wqh = alloc((size_t)HY * Dd);
  f16* Wkh = alloc((size_t)HY * Dd);
  f16* WqT = alloc((size_t)Dd * HY);
  f16* WkT = alloc((size_t)Dd * HY);
  f16* xih = alloc((size_t)Mm * Dd);
  f16* xiT = alloc((size_t)Dd * Mm);
  f16* SP  = alloc((size_t)48 * Nn * Nn);      // P; aliased: update partial slices 0..3
  f16* PTH = alloc((size_t)48 * Nn * Nn);      // P^T, later reused as hid [4096][3072]
  f16* hid = PTH;                              // same element count: 48*512*512 == 4096*3072
  if (used > ws_size) return;

  hipMemcpyAsync(x, x_in, SZ * sizeof(float), hipMemcpyDeviceToDevice, stream);

  // one-time weight conversion + transposes
  k_cvt_tr<<<dim3(Dd / 64, HY / 64), 256, 0, stream>>>(Wq, HY, Dd, Wqh, WqT);
  k_cvt_tr<<<dim3(Dd / 64, HY / 64), 256, 0, stream>>>(Wk, HY, Dd, Wkh, WkT);
  k_cvt_tr<<<dim3(Dd / 64, Mm / 64), 256, 0, stream>>>(xi, Mm, Dd, xih, xiT);

  for (int step = 0; step < 12; ++step) {
    if (step == 0)
      k_ln<<<BN_TOT, 256, 0, stream>>>(x, gamma, delta, g);
    else
      k_lnred<<<BN_TOT, 256, 0, stream>>>(x, gamma, delta, g, SP, q, k);
    k_qkproj<<<dim3(6, 32, 2), 256, 0, stream>>>(g, Wqh, Wkh, q, k, qT, kT);
    for (int half = 0; half < 2; ++half) {
      int zbase = half * 48;
      k_attn<<<dim3(16, 48), 256, 0, stream>>>(q, k, SP, PTH, zbase);
      k_dqdk<<<dim3(1, Nn / 128, 96), 256, 0, stream>>>(SP, PTH, qT, kT, dq, dk, zbase);
    }
    k_hid<<<dim3(24, 32), 256, 0, stream>>>(g, xih, hid);
    k_update<<<dim3(6, 32, 6), 256, 0, stream>>>(dq, dk, WqT, WkT, hid, xiT, SP, q, k);
  }
  k_redfin<<<BN_TOT, 256, 0, stream>>>(x, SP, q, k);
}